// Round 6
// baseline (1347.085 us; speedup 1.0000x reference)
//
#include <hip/hip_runtime.h>
#include <math.h>

#define Dm    2048
#define Hh    6
#define DKk   256
#define DVv   512
#define KD    1536
#define VD    3072
#define QGW   4608
#define CH    4

typedef __attribute__((ext_vector_type(8))) __bf16 bf16x8;
typedef __attribute__((ext_vector_type(4))) float floatx4;

__device__ __forceinline__ unsigned short f2bf(float f) {
    unsigned int u = __float_as_uint(f);
    u = (u + 0x7fffu + ((u >> 16) & 1u)) >> 16;
    return (unsigned short)u;
}

__device__ __forceinline__ void gl_lds16(const void* g, void* l) {
    __builtin_amdgcn_global_load_lds((const __attribute__((address_space(1))) void*)g,
                                     (__attribute__((address_space(3))) void*)l, 16, 0, 0);
}

// ---------------------------------------------------------------- router ----
__global__ void router_kernel(const float* __restrict__ hidden,
                              const float* __restrict__ gate_w,
                              int* __restrict__ sel01, float* __restrict__ w01)
{
    int t = blockIdx.x;
    int lane = threadIdx.x;                      // 64 threads
    const float* hr = hidden + (size_t)t * Dm;
    float h[32];
#pragma unroll
    for (int i = 0; i < 32; ++i) h[i] = hr[lane + 64 * i];
    float logit[8];
#pragma unroll
    for (int e = 0; e < 8; ++e) {
        float acc = 0.f;
#pragma unroll
        for (int i = 0; i < 32; ++i) acc += h[i] * gate_w[(size_t)(lane + 64 * i) * 8 + e];
#pragma unroll
        for (int off = 1; off < 64; off <<= 1) acc += __shfl_xor(acc, off, 64);
        logit[e] = acc;
    }
    if (lane == 0) {
        int i0 = 0;
#pragma unroll
        for (int e = 1; e < 8; ++e) if (logit[e] > logit[i0]) i0 = e;
        int i1 = (i0 == 0) ? 1 : 0;
#pragma unroll
        for (int e = 0; e < 8; ++e) if (e != i0 && logit[e] > logit[i1]) i1 = e;
        float w0 = 1.f / (1.f + expf(logit[i1] - logit[i0]));
        sel01[2 * t] = i0; sel01[2 * t + 1] = i1;
        w01[2 * t] = w0;   w01[2 * t + 1] = 1.f - w0;
    }
}

// -------------------------------------------------------------- dispatch ----
__global__ void dispatch_kernel(const int* __restrict__ sel01,
                                int* __restrict__ list_c, int* __restrict__ posg,
                                int* __restrict__ cnt, int* __restrict__ basearr)
{
    __shared__ int wbase[16];
    __shared__ int sbase;
    int t = threadIdx.x;
    int lane = t & 63, w = t >> 6;
    int s0 = sel01[2 * t], s1 = sel01[2 * t + 1];
    if (t == 0) sbase = 0;
    __syncthreads();
    for (int e = 0; e < 8; ++e) {
        int flag  = (s0 == e || s1 == e) ? 1 : 0;
        int kslot = (s0 == e) ? 0 : 1;
        unsigned long long m = __ballot(flag);
        int lpre = __popcll(m & ((1ull << lane) - 1ull));
        if (lane == 0) wbase[w] = __popcll(m);
        __syncthreads();
        if (t == 0) {
            int run = sbase;
            basearr[e] = run;
            for (int i = 0; i < 16; ++i) { int tv = wbase[i]; wbase[i] = run; run += tv; }
            cnt[e] = run - sbase;
            sbase = run;
        }
        __syncthreads();
        if (flag) {
            int pos = wbase[w] + lpre;
            list_c[pos] = t;
            posg[2 * t + kslot] = pos;
        }
        __syncthreads();
    }
}

// ------------------------------------------------------------ bf16 casts ----
__global__ void cast_bf16_kernel(const float* __restrict__ x, unsigned short* __restrict__ y)
{
    int i = (blockIdx.x * 256 + threadIdx.x) * 4;
    float4 a = *(const float4*)(x + i);
    ushort4 o;
    o.x = f2bf(a.x); o.y = f2bf(a.y); o.z = f2bf(a.z); o.w = f2bf(a.w);
    *(ushort4*)(y + i) = o;
}

__global__ void gather_cast_kernel(const float* __restrict__ hidden, const int* __restrict__ list,
                                   unsigned short* __restrict__ xe)
{
    int slot = blockIdx.x;
    int tok = list[slot];
    const float* src = hidden + (size_t)tok * Dm;
    unsigned short* dst = xe + (size_t)slot * Dm;
    int c = threadIdx.x * 8;
    float4 a = *(const float4*)(src + c);
    float4 b = *(const float4*)(src + c + 4);
    ushort4 o1, o2;
    o1.x = f2bf(a.x); o1.y = f2bf(a.y); o1.z = f2bf(a.z); o1.w = f2bf(a.w);
    o2.x = f2bf(b.x); o2.y = f2bf(b.y); o2.z = f2bf(b.z); o2.w = f2bf(b.w);
    *(ushort4*)(dst + c) = o1;
    *(ushort4*)(dst + c + 4) = o2;
}

// fp32 [b][K][N] -> bf16 [b][N][K] at expert stride estride (fused buffers).
__global__ void transpose_cast_kernel(const float* __restrict__ in, unsigned short* __restrict__ out,
                                      int K, int N, size_t estride)
{
    __shared__ float tile[32][33];
    int b = blockIdx.z;
    int k0 = blockIdx.x * 32, n0 = blockIdx.y * 32;
    const float* ip = in + (size_t)b * K * N;
    unsigned short* op = out + (size_t)b * estride;
    int tx = threadIdx.x & 31, ty = threadIdx.x >> 5;   // 32 x 8
#pragma unroll
    for (int i = 0; i < 4; ++i)
        tile[ty + i * 8][tx] = ip[(size_t)(k0 + ty + i * 8) * N + n0 + tx];
    __syncthreads();
#pragma unroll
    for (int i = 0; i < 4; ++i)
        op[(size_t)(n0 + ty + i * 8) * K + k0 + tx] = f2bf(tile[tx][ty + i * 8]);
}

// ----------------------------------------------------------- bf16 GEMM ------
// C[M][N] = A[M][K] * Bt[N][K]^T, 128x128 tile, BK=32, mfma 16x16x32 bf16.
// Depth-3 software pipeline, 4 LDS buffers, counted vmcnt fused into the
// barrier asm so hipcc cannot insert its own vmcnt(0) drain.
// R5: q+g and k+v merged into N=4608 launches (shared A panels; q-GEMM was
// 96 blocks = 0.37 blocks/CU, 63% of CUs idle).
template<bool EXPERT>
__global__ __launch_bounds__(256)
void gemm_bf16(const unsigned short* __restrict__ A,
               const unsigned short* __restrict__ Bt,
               float* __restrict__ C,
               const int* __restrict__ cnt, const int* __restrict__ basearr,
               int M, int K, int N)
{
    int e = EXPERT ? blockIdx.z : 0;
    int Mloc = M, base = 0;
    if (EXPERT) {
        Mloc = cnt[e]; base = basearr[e];
        if ((int)(blockIdx.x * 128) >= Mloc) return;
    }
    int m0 = blockIdx.x * 128, n0 = blockIdx.y * 128;
    const unsigned short* Ab = A + (size_t)base * K;
    const unsigned short* Bb = Bt + (size_t)e * (size_t)K * N;
    __shared__ unsigned short As[4][128 * 32];
    __shared__ unsigned short Bs[4][128 * 32];
    int tid = threadIdx.x;
    int lane = tid & 63, wave = tid >> 6;
    const unsigned short* ga[2];
    const unsigned short* gb[2];
    int lo[2];
#pragma unroll
    for (int j = 0; j < 2; ++j) {
        int flat = j * 256 + tid;
        int row = flat >> 2, sub = flat & 3;
        int ar = m0 + row; if (ar > Mloc - 1) ar = Mloc - 1;
        ga[j] = Ab + (size_t)ar * K + sub * 8;
        gb[j] = Bb + (size_t)(n0 + row) * K + sub * 8;
        lo[j] = flat * 8;
    }
    floatx4 acc[4][4];
#pragma unroll
    for (int i = 0; i < 4; ++i)
#pragma unroll
        for (int j = 0; j < 4; ++j) acc[i][j] = (floatx4){0.f, 0.f, 0.f, 0.f};

    int wm = (wave >> 1) * 64, wn = (wave & 1) * 64;
    int fr = lane & 15, kr = (lane >> 4) * 8;

    int nk = K >> 5;
    auto stage = [&](int buf, int t) {
        int k0 = t << 5;
        gl_lds16(ga[0] + k0, As[buf] + lo[0]);
        gl_lds16(gb[0] + k0, Bs[buf] + lo[0]);
        gl_lds16(ga[1] + k0, As[buf] + lo[1]);
        gl_lds16(gb[1] + k0, Bs[buf] + lo[1]);
    };
    stage(0, 0);
    stage(1, 1);
    stage(2, 2);
    int cur = 0;
    for (int t = 0; t < nk; ++t) {
        int nxt = (cur + 3) & 3;
        if (t + 3 < nk) stage(nxt, t + 3);
        int ahead = nk - 1 - t;
        if (ahead >= 3)      asm volatile("s_waitcnt vmcnt(12)\n\ts_barrier" ::: "memory");
        else if (ahead == 2) asm volatile("s_waitcnt vmcnt(8)\n\ts_barrier" ::: "memory");
        else if (ahead == 1) asm volatile("s_waitcnt vmcnt(4)\n\ts_barrier" ::: "memory");
        else                 asm volatile("s_waitcnt vmcnt(0)\n\ts_barrier" ::: "memory");
        bf16x8 af[4], bfr[4];
        const unsigned short* Ac = As[cur];
        const unsigned short* Bc = Bs[cur];
#pragma unroll
        for (int f = 0; f < 4; ++f) {
            af[f]  = *(const bf16x8*)(Ac + (size_t)(wm + f * 16 + fr) * 32 + kr);
            bfr[f] = *(const bf16x8*)(Bc + (size_t)(wn + f * 16 + fr) * 32 + kr);
        }
#pragma unroll
        for (int fm = 0; fm < 4; ++fm)
#pragma unroll
            for (int fn = 0; fn < 4; ++fn)
                acc[fm][fn] = __builtin_amdgcn_mfma_f32_16x16x32_bf16(af[fm], bfr[fn], acc[fm][fn], 0, 0, 0);
        asm volatile("s_waitcnt lgkmcnt(0)\n\ts_barrier" ::: "memory");
        cur = (cur + 1) & 3;
    }
    int rb = (lane >> 4) * 4;
#pragma unroll
    for (int fm = 0; fm < 4; ++fm) {
#pragma unroll
        for (int r = 0; r < 4; ++r) {
            int m = m0 + wm + fm * 16 + rb + r;
            if (m < Mloc) {
                float* cp = C + (size_t)(base + m) * N + n0 + wn + fr;
#pragma unroll
                for (int fn = 0; fn < 4; ++fn)
                    cp[fn * 16] = acc[fm][fn][r];
            }
        }
    }
}

// ------------------------------------------- beta / g small projections ----
__global__ void ba_kernel(const float* __restrict__ hidden,
                          const float* __restrict__ b_w, const float* __restrict__ a_w,
                          const float* __restrict__ A_log, const float* __restrict__ dt_bias,
                          const int* __restrict__ list, const int* __restrict__ cnt,
                          const int* __restrict__ basearr,
                          float* __restrict__ beta_c, float* __restrict__ g_c)
{
    int j = blockIdx.x, e = blockIdx.y;
    if (j >= cnt[e]) return;
    int gpos = basearr[e] + j;
    int tok = list[gpos];
    int lane = threadIdx.x;                      // 64
    const float* hr = hidden + (size_t)tok * Dm;
    float h[32];
#pragma unroll
    for (int i = 0; i < 32; ++i) h[i] = hr[lane + 64 * i];
    for (int c = 0; c < 12; ++c) {
        int col = c % 6;
        const float* W = ((c < 6) ? b_w : a_w) + (size_t)e * Dm * 6;
        float acc = 0.f;
#pragma unroll
        for (int i = 0; i < 32; ++i) acc += h[i] * W[(size_t)(lane + 64 * i) * 6 + col];
#pragma unroll
        for (int off = 1; off < 64; off <<= 1) acc += __shfl_xor(acc, off, 64);
        if (lane == 0) {
            if (c < 6) {
                beta_c[gpos * 6 + col] = 1.f / (1.f + expf(-acc));
            } else {
                float x = acc + dt_bias[col];
                float sp = (x > 20.f) ? x : log1pf(expf(x));
                g_c[gpos * 6 + col] = -expf(A_log[col]) * sp;
            }
        }
    }
}

// -------------------------------------- causal conv4 + silu (+ l2 norm) ----
// X rows at stride xstride (fused qg / kv buffers, cols 0..KD-1).
template<bool GATHER>
__global__ void conv_norm_kernel(const float* __restrict__ X, int xstride,
                                 const float* __restrict__ convw,
                                 const int* __restrict__ list, const int* __restrict__ cnt,
                                 const int* __restrict__ basearr,
                                 float* __restrict__ outb, float scale)
{
    int j = blockIdx.x, e = blockIdx.y, h = blockIdx.z;
    if (j >= cnt[e]) return;
    int base = basearr[e];
    int gpos = base + j;
    int c = h * DKk + threadIdx.x;               // 256 threads
    float acc = 0.f;
#pragma unroll
    for (int tau = 0; tau < 4; ++tau) {
        int jj = j - 3 + tau;
        if (jj >= 0) {
            const float* row = GATHER ? (X + (size_t)list[base + jj] * xstride)
                                      : (X + (size_t)(base + jj) * xstride);
            acc += row[c] * convw[c * 4 + tau];
        }
    }
    float y = acc / (1.f + expf(-acc));          // silu
    float v = y * y;
#pragma unroll
    for (int off = 1; off < 64; off <<= 1) v += __shfl_xor(v, off, 64);
    __shared__ float red[4];
    if ((threadIdx.x & 63) == 0) red[threadIdx.x >> 6] = v;
    __syncthreads();
    float total = red[0] + red[1] + red[2] + red[3];
    outb[(size_t)gpos * KD + c] = y * rsqrtf(total + 1e-6f) * scale;
}

// v-conv reads fused kv rows, cols KD..KD+VD-1.
__global__ void conv_v_kernel(const float* __restrict__ X,
                              const float* __restrict__ convw,
                              const int* __restrict__ cnt, const int* __restrict__ basearr,
                              float* __restrict__ outb)
{
    int j = blockIdx.x, e = blockIdx.y;
    if (j >= cnt[e]) return;
    int base = basearr[e];
    int gpos = base + j;
    int c = blockIdx.z * 256 + threadIdx.x;      // 12 * 256 = 3072
    float acc = 0.f;
#pragma unroll
    for (int tau = 0; tau < 4; ++tau) {
        int jj = j - 3 + tau;
        if (jj >= 0) acc += X[(size_t)(base + jj) * QGW + KD + c] * convw[c * 4 + tau];
    }
    outb[(size_t)gpos * VD + c] = acc / (1.f + expf(-acc));
}

// ------------------------------------------------ qk = q . k precompute ----
__global__ void qk_kernel(const float* __restrict__ qn, const float* __restrict__ kn,
                          float* __restrict__ qk_c)
{
    int gpos = blockIdx.x, h = blockIdx.y;
    int lane = threadIdx.x;                      // 64
    const float4* qp = (const float4*)(qn + (size_t)gpos * KD + h * DKk);
    const float4* kp = (const float4*)(kn + (size_t)gpos * KD + h * DKk);
    float4 a = qp[lane], b = kp[lane];
    float acc = a.x * b.x + a.y * b.y + a.z * b.z + a.w * b.w;
#pragma unroll
    for (int off = 1; off < 64; off <<= 1) acc += __shfl_xor(acc, off, 64);
    if (lane == 0) qk_c[(size_t)gpos * Hh + h] = acc;
}

// --------------------------------------------- gated delta rule (serial) ----
// R5: grid (32, H, E) = 1536 blocks (was 768: only 3 blocks/CU, VALUBusy 70%,
// Occupancy 29.6% -> latency partly exposed). thread = (kpart 0..15,
// vcol 0..15), 16 state floats/thread; per-wave chain per step halves, waves
// per SIMD ~doubles. Redundant k/q re-reads (16x->32x) hit L2/L3 (measured
// FETCH only 112 MB). LDS reads: lane float4 at kpart*16B + i*256B -> 16
// distinct addrs, 2 per bank = free 2-way (m136); same-addr 4-lane broadcast.
// shfl reduce over kpart: masks 1,2,4,8. Staging/vmcnt ledger identical to
// the HW-verified R4 version (loadScal still 16 vm loads).
__global__ __launch_bounds__(256, 4)
void recurrence_kernel(const float* __restrict__ qn, const float* __restrict__ kn,
                       const float* __restrict__ vc,
                       const float* __restrict__ beta_c, const float* __restrict__ g_c,
                       const float* __restrict__ qk_c,
                       const int* __restrict__ cnt, const int* __restrict__ basearr,
                       float* __restrict__ o_c)
{
    int vb = blockIdx.x, h = blockIdx.y, e = blockIdx.z;
    int n = cnt[e], base = basearr[e];
    if (n <= 0) return;
    int tid = threadIdx.x;
    int kpart = tid & 15, vcol = tid >> 4;       // 16 x 16
    int v = vb * 16 + vcol;
    int wv = tid >> 6, lane = tid & 63;

    __shared__ float lk[2][CH][256];             // 8 KB
    __shared__ float lq[2][CH][256];             // 8 KB

    const float* kb = kn + (size_t)base * KD + h * DKk;
    const float* qb = qn + (size_t)base * KD + h * DKk;
    const float* vp = vc + (size_t)base * VD + h * DVv + v;
    const float* gp = g_c    + (size_t)base * Hh + h;
    const float* bp = beta_c + (size_t)base * Hh + h;
    const float* xp = qk_c   + (size_t)base * Hh + h;
    float* op = o_c + (size_t)base * VD + h * DVv + v;

    float4 s[4];
#pragma unroll
    for (int i = 0; i < 4; ++i) s[i] = make_float4(0.f, 0.f, 0.f, 0.f);

    int nch = (n + CH - 1) / CH;

    // wave wv stages row wv of the chunk: 1 k-row + 1 q-row = 2 vm insts/wave.
    auto stageKQ = [&](int buf, int c) {
        int jj = c * CH + wv; if (jj > n - 1) jj = n - 1;
        gl_lds16(kb + (size_t)jj * KD + lane * 4, &lk[buf][wv][lane * 4]);
        gl_lds16(qb + (size_t)jj * KD + lane * 4, &lq[buf][wv][lane * 4]);
    };

    float vA[CH], gA[CH], bA[CH], xA[CH];
    float vB[CH], gB[CH], bB[CH], xB[CH];

    auto loadScal = [&](float (&V)[CH], float (&G)[CH], float (&B)[CH], float (&X)[CH], int c) {
#pragma unroll
        for (int u = 0; u < CH; ++u) {
            int jj = c * CH + u; if (jj > n - 1) jj = n - 1;
            V[u] = vp[(size_t)jj * VD];
            G[u] = gp[(size_t)jj * Hh];
            B[u] = bp[(size_t)jj * Hh];
            X[u] = xp[(size_t)jj * Hh];
        }
    };

    auto computeChunk = [&](const float (&Lk)[CH][256], const float (&Lq)[CH][256],
                            const float (&V)[CH], const float (&G)[CH],
                            const float (&B)[CH], const float (&X)[CH], int c) {
#pragma unroll
        for (int u = 0; u < CH; ++u) {
            // lane owns k-dims {kpart*4 + j + i*64}: all 256 dims covered once.
            const float* Lku = &Lk[u][kpart * 4];
            const float* Lqu = &Lq[u][kpart * 4];
            float4 pa0 = make_float4(0.f,0.f,0.f,0.f), pa1 = make_float4(0.f,0.f,0.f,0.f);
            float4 ra0 = make_float4(0.f,0.f,0.f,0.f), ra1 = make_float4(0.f,0.f,0.f,0.f);
            float4 kk[4];
#pragma unroll
            for (int i = 0; i < 4; ++i) {
                kk[i] = *(const float4*)(Lku + i * 64);
                float4 qq = *(const float4*)(Lqu + i * 64);
                float4& pa = (i & 1) ? pa1 : pa0;
                float4& ra = (i & 1) ? ra1 : ra0;
                pa.x = fmaf(kk[i].x, s[i].x, pa.x); pa.y = fmaf(kk[i].y, s[i].y, pa.y);
                pa.z = fmaf(kk[i].z, s[i].z, pa.z); pa.w = fmaf(kk[i].w, s[i].w, pa.w);
                ra.x = fmaf(qq.x, s[i].x, ra.x); ra.y = fmaf(qq.y, s[i].y, ra.y);
                ra.z = fmaf(qq.z, s[i].z, ra.z); ra.w = fmaf(qq.w, s[i].w, ra.w);
            }
            float p = ((pa0.x + pa1.x) + (pa0.y + pa1.y)) + ((pa0.z + pa1.z) + (pa0.w + pa1.w));
            float r = ((ra0.x + ra1.x) + (ra0.y + ra1.y)) + ((ra0.z + ra1.z) + (ra0.w + ra1.w));
#pragma unroll
            for (int m = 1; m < 16; m <<= 1) {
                p += __shfl_xor(p, m, 64);
                r += __shfl_xor(r, m, 64);
            }
            float eg = __expf(G[u]);
            float delta = (V[u] - p * eg) * B[u];
            float out = fmaf(X[u], delta, eg * r);
#pragma unroll
            for (int i = 0; i < 4; ++i) {
                s[i].x = fmaf(eg, s[i].x, kk[i].x * delta);
                s[i].y = fmaf(eg, s[i].y, kk[i].y * delta);
                s[i].z = fmaf(eg, s[i].z, kk[i].z * delta);
                s[i].w = fmaf(eg, s[i].w, kk[i].w * delta);
            }
            int j = c * CH + u;
            if (kpart == 0 && j < n) op[(size_t)j * VD] = out;
        }
    };

    // prologue: chunk0 kq + scalars, chunk1 kq in flight.
    stageKQ(0, 0);
    loadScal(vA, gA, bA, xA, 0);
    stageKQ(1, 1);
    asm volatile("s_waitcnt vmcnt(2)\n\ts_barrier" ::: "memory");

    for (int c = 0; c < nch; c += 2) {
        loadScal(vB, gB, bB, xB, c + 1);         // clamped; uniform vm counts
        computeChunk(lk[0], lq[0], vA, gA, bA, xA, c);
        __syncthreads();                          // all waves done reading lk[0]
        stageKQ(0, c + 2);                        // clamped (always 2 insts)
        asm volatile("s_waitcnt vmcnt(2)\n\ts_barrier" ::: "memory");
        if (c + 1 >= nch) break;
        loadScal(vA, gA, bA, xA, c + 2);
        computeChunk(lk[1], lq[1], vB, gB, bB, xB, c + 1);
        __syncthreads();
        stageKQ(1, c + 3);
        asm volatile("s_waitcnt vmcnt(2)\n\ts_barrier" ::: "memory");
    }
    asm volatile("s_waitcnt vmcnt(0)" ::: "memory");   // drain tail staging
}

// ------------------------------- combine + gated RMSNorm (swish gate) -------
// gate read from the fused qg buffer (cols KD..KD+VD-1 of row t).
__global__ void combine_kernel(const float* __restrict__ o_c, const float* __restrict__ qg,
                               const float* __restrict__ norm_w,
                               const int* __restrict__ posg, const float* __restrict__ w01,
                               unsigned short* __restrict__ ocg)
{
    int t = blockIdx.x, h = blockIdx.y;
    int p0 = posg[2 * t], p1 = posg[2 * t + 1];
    float w0 = w01[2 * t], w1 = w01[2 * t + 1];
    int v0 = threadIdx.x, v1 = threadIdx.x + 256;
    size_t r0 = (size_t)p0 * VD + h * DVv, r1 = (size_t)p1 * VD + h * DVv;
    float a  = w0 * o_c[r0 + v0] + w1 * o_c[r1 + v0];
    float b2 = w0 * o_c[r0 + v1] + w1 * o_c[r1 + v1];
    float val = a * a + b2 * b2;
#pragma unroll
    for (int off = 1; off < 64; off <<= 1) val += __shfl_xor(val, off, 64);
    __shared__ float red[4];
    if ((threadIdx.x & 63) == 0) red[threadIdx.x >> 6] = val;
    __syncthreads();
    float total = red[0] + red[1] + red[2] + red[3];
    float rms = rsqrtf(total / 512.f + 1e-5f);
    size_t og = (size_t)t * VD + h * DVv;
    size_t gq = (size_t)t * QGW + KD + h * DVv;
    float g0 = qg[gq + v0], g1 = qg[gq + v1];
    ocg[og + v0] = f2bf(a  * rms * norm_w[v0] * g0 / (1.f + expf(-g0)));
    ocg[og + v1] = f2bf(b2 * rms * norm_w[v1] * g1 / (1.f + expf(-g1)));
}

// ------------------------------------------------------------------ host ----
extern "C" void kernel_launch(void* const* d_in, const int* in_sizes, int n_in,
                              void* d_out, int out_size, void* d_ws, size_t ws_size,
                              hipStream_t stream)
{
    const float* hidden   = (const float*)d_in[0];
    const float* q_w      = (const float*)d_in[1];
    const float* gate_w   = (const float*)d_in[2];
    const float* k_w      = (const float*)d_in[3];
    const float* v_w      = (const float*)d_in[4];
    const float* b_w      = (const float*)d_in[5];
    const float* a_w      = (const float*)d_in[6];
    const float* A_log    = (const float*)d_in[7];
    const float* dt_bias  = (const float*)d_in[8];
    const float* q_conv_w = (const float*)d_in[9];
    const float* k_conv_w = (const float*)d_in[10];
    const float* v_conv_w = (const float*)d_in[11];
    const float* g_w      = (const float*)d_in[12];
    const float* norm_w   = (const float*)d_in[13];
    const float* o_w      = (const float*)d_in[14];
    float* outp = (float*)d_out;

    float* f = (float*)d_ws;
    size_t off = 0;
    auto alloc = [&](size_t n) { float* p = f + off; off += (n + 3) & ~(size_t)3; return p; };
    float* qg     = alloc((size_t)1024 * QGW);    // [t][0:1536]=qh, [1536:4608]=gg
    float* kvraw  = alloc((size_t)2048 * QGW);    // [slot][0:1536]=kraw, [1536:4608]=vraw
    float* qn     = alloc((size_t)2048 * 1536);
    float* kn     = alloc((size_t)2048 * 1536);
    float* vconv  = alloc((size_t)2048 * 3072);
    float* o_c    = alloc((size_t)2048 * 3072);
    float* beta_c = alloc(2048 * 6);
    float* g_c    = alloc(2048 * 6);
    float* qk_c   = alloc(2048 * 6);
    float* w01f   = alloc(2048);

    unsigned short* u = (unsigned short*)(f + off);
    size_t uoff = 0;
    auto ualloc = [&](size_t n) { unsigned short* p = u + uoff; uoff += (n + 7) & ~(size_t)7; return p; };
    unsigned short* hidden_bf = ualloc((size_t)1024 * 2048);
    unsigned short* xe_c      = ualloc((size_t)2048 * 2048);
    unsigned short* ocg       = ualloc((size_t)1024 * 3072);
    unsigned short* qg_wT     = ualloc((size_t)QGW * 2048);       // q rows 0-1535, g rows 1536-4607
    unsigned short* kv_wT     = ualloc((size_t)8 * QGW * 2048);   // per e: k rows 0-1535, v rows 1536-4607
    unsigned short* o_wT      = ualloc((size_t)3072 * 2048);

    int* ib      = (int*)(u + uoff);
    int* sel01   = ib;
    int* list_c  = ib + 2048;
    int* posg    = ib + 4096;
    int* cnt     = ib + 6144;
    int* basearr = ib + 6152;

    const size_t EST = (size_t)2048 * QGW;       // expert stride in fused kv_wT

    router_kernel<<<1024, 64, 0, stream>>>(hidden, gate_w, sel01, w01f);
    dispatch_kernel<<<1, 1024, 0, stream>>>(sel01, list_c, posg, cnt, basearr);

    cast_bf16_kernel<<<2048, 256, 0, stream>>>(hidden, hidden_bf);
    gather_cast_kernel<<<2048, 256, 0, stream>>>(hidden, list_c, xe_c);
    transpose_cast_kernel<<<dim3(64, 48, 1), 256, 0, stream>>>(q_w, qg_wT, 2048, 1536, 0);
    transpose_cast_kernel<<<dim3(64, 96, 1), 256, 0, stream>>>(g_w, qg_wT + (size_t)1536 * 2048, 2048, 3072, 0);
    transpose_cast_kernel<<<dim3(64, 48, 8), 256, 0, stream>>>(k_w, kv_wT, 2048, 1536, EST);
    transpose_cast_kernel<<<dim3(64, 96, 8), 256, 0, stream>>>(v_w, kv_wT + (size_t)1536 * 2048, 2048, 3072, EST);
    transpose_cast_kernel<<<dim3(96, 64, 1), 256, 0, stream>>>(o_w, o_wT, 3072, 2048, 0);

    gemm_bf16<false><<<dim3(8, 36), 256, 0, stream>>>(hidden_bf, qg_wT, qg, nullptr, nullptr, 1024, 2048, QGW);
    gemm_bf16<true ><<<dim3(8, 36, 8), 256, 0, stream>>>(xe_c, kv_wT, kvraw, cnt, basearr, 0, 2048, QGW);

    ba_kernel<<<dim3(1024, 8), 64, 0, stream>>>(hidden, b_w, a_w, A_log, dt_bias,
                                                list_c, cnt, basearr, beta_c, g_c);

    conv_norm_kernel<true ><<<dim3(1024, 8, 6), 256, 0, stream>>>(qg,    QGW, q_conv_w, list_c, cnt, basearr, qn, 0.0625f);
    conv_norm_kernel<false><<<dim3(1024, 8, 6), 256, 0, stream>>>(kvraw, QGW, k_conv_w, list_c, cnt, basearr, kn, 1.0f);
    conv_v_kernel<<<dim3(1024, 8, 12), 256, 0, stream>>>(kvraw, v_conv_w, cnt, basearr, vconv);

    qk_kernel<<<dim3(2048, 6), 64, 0, stream>>>(qn, kn, qk_c);

    recurrence_kernel<<<dim3(32, 6, 8), 256, 0, stream>>>(qn, kn, vconv, beta_c, g_c, qk_c,
                                                          cnt, basearr, o_c);

    combine_kernel<<<dim3(1024, 6), 256, 0, stream>>>(o_c, qg, norm_w, posg, w01f, ocg);
    gemm_bf16<false><<<dim3(8, 16), 256, 0, stream>>>(ocg, o_wT, outp, nullptr, nullptr, 1024, 3072, 2048);
}

// Round 7
// 1232.949 us; speedup vs baseline: 1.0926x; 1.0926x over previous
//
#include <hip/hip_runtime.h>
#include <math.h>

#define Dm    2048
#define Hh    6
#define DKk   256
#define DVv   512
#define KD    1536
#define VD    3072
#define QGW   4608
#define CH    4

typedef __attribute__((ext_vector_type(8))) __bf16 bf16x8;
typedef __attribute__((ext_vector_type(4))) float floatx4;

__device__ __forceinline__ unsigned short f2bf(float f) {
    unsigned int u = __float_as_uint(f);
    u = (u + 0x7fffu + ((u >> 16) & 1u)) >> 16;
    return (unsigned short)u;
}

__device__ __forceinline__ void gl_lds16(const void* g, void* l) {
    __builtin_amdgcn_global_load_lds((const __attribute__((address_space(1))) void*)g,
                                     (__attribute__((address_space(3))) void*)l, 16, 0, 0);
}

// ---------------------------------------------------------------- router ----
__global__ void router_kernel(const float* __restrict__ hidden,
                              const float* __restrict__ gate_w,
                              int* __restrict__ sel01, float* __restrict__ w01)
{
    int t = blockIdx.x;
    int lane = threadIdx.x;                      // 64 threads
    const float* hr = hidden + (size_t)t * Dm;
    float h[32];
#pragma unroll
    for (int i = 0; i < 32; ++i) h[i] = hr[lane + 64 * i];
    float logit[8];
#pragma unroll
    for (int e = 0; e < 8; ++e) {
        float acc = 0.f;
#pragma unroll
        for (int i = 0; i < 32; ++i) acc += h[i] * gate_w[(size_t)(lane + 64 * i) * 8 + e];
#pragma unroll
        for (int off = 1; off < 64; off <<= 1) acc += __shfl_xor(acc, off, 64);
        logit[e] = acc;
    }
    if (lane == 0) {
        int i0 = 0;
#pragma unroll
        for (int e = 1; e < 8; ++e) if (logit[e] > logit[i0]) i0 = e;
        int i1 = (i0 == 0) ? 1 : 0;
#pragma unroll
        for (int e = 0; e < 8; ++e) if (e != i0 && logit[e] > logit[i1]) i1 = e;
        float w0 = 1.f / (1.f + expf(logit[i1] - logit[i0]));
        sel01[2 * t] = i0; sel01[2 * t + 1] = i1;
        w01[2 * t] = w0;   w01[2 * t + 1] = 1.f - w0;
    }
}

// -------------------------------------------------------------- dispatch ----
__global__ void dispatch_kernel(const int* __restrict__ sel01,
                                int* __restrict__ list_c, int* __restrict__ posg,
                                int* __restrict__ cnt, int* __restrict__ basearr)
{
    __shared__ int wbase[16];
    __shared__ int sbase;
    int t = threadIdx.x;
    int lane = t & 63, w = t >> 6;
    int s0 = sel01[2 * t], s1 = sel01[2 * t + 1];
    if (t == 0) sbase = 0;
    __syncthreads();
    for (int e = 0; e < 8; ++e) {
        int flag  = (s0 == e || s1 == e) ? 1 : 0;
        int kslot = (s0 == e) ? 0 : 1;
        unsigned long long m = __ballot(flag);
        int lpre = __popcll(m & ((1ull << lane) - 1ull));
        if (lane == 0) wbase[w] = __popcll(m);
        __syncthreads();
        if (t == 0) {
            int run = sbase;
            basearr[e] = run;
            for (int i = 0; i < 16; ++i) { int tv = wbase[i]; wbase[i] = run; run += tv; }
            cnt[e] = run - sbase;
            sbase = run;
        }
        __syncthreads();
        if (flag) {
            int pos = wbase[w] + lpre;
            list_c[pos] = t;
            posg[2 * t + kslot] = pos;
        }
        __syncthreads();
    }
}

// ------------------------------------------------------------ bf16 casts ----
__global__ void cast_bf16_kernel(const float* __restrict__ x, unsigned short* __restrict__ y)
{
    int i = (blockIdx.x * 256 + threadIdx.x) * 4;
    float4 a = *(const float4*)(x + i);
    ushort4 o;
    o.x = f2bf(a.x); o.y = f2bf(a.y); o.z = f2bf(a.z); o.w = f2bf(a.w);
    *(ushort4*)(y + i) = o;
}

__global__ void gather_cast_kernel(const float* __restrict__ hidden, const int* __restrict__ list,
                                   unsigned short* __restrict__ xe)
{
    int slot = blockIdx.x;
    int tok = list[slot];
    const float* src = hidden + (size_t)tok * Dm;
    unsigned short* dst = xe + (size_t)slot * Dm;
    int c = threadIdx.x * 8;
    float4 a = *(const float4*)(src + c);
    float4 b = *(const float4*)(src + c + 4);
    ushort4 o1, o2;
    o1.x = f2bf(a.x); o1.y = f2bf(a.y); o1.z = f2bf(a.z); o1.w = f2bf(a.w);
    o2.x = f2bf(b.x); o2.y = f2bf(b.y); o2.z = f2bf(b.z); o2.w = f2bf(b.w);
    *(ushort4*)(dst + c) = o1;
    *(ushort4*)(dst + c + 4) = o2;
}

// fp32 [b][K][N] -> bf16 [b][N][K] at expert stride estride (fused buffers).
// R6: write phase vectorized -- thread (kq=tid&7, n=tid>>3) emits one ushort4
// (4 consecutive K values, 8B store; was 4x scalar 2B stores). LDS read banks
// (4kq+j+n)%32: worst 2-way (free, m136).
__global__ void transpose_cast_kernel(const float* __restrict__ in, unsigned short* __restrict__ out,
                                      int K, int N, size_t estride)
{
    __shared__ float tile[32][33];
    int b = blockIdx.z;
    int k0 = blockIdx.x * 32, n0 = blockIdx.y * 32;
    const float* ip = in + (size_t)b * K * N;
    unsigned short* op = out + (size_t)b * estride;
    int tx = threadIdx.x & 31, ty = threadIdx.x >> 5;   // 32 x 8 load phase
#pragma unroll
    for (int i = 0; i < 4; ++i)
        tile[ty + i * 8][tx] = ip[(size_t)(k0 + ty + i * 8) * N + n0 + tx];
    __syncthreads();
    int kq = threadIdx.x & 7, n = threadIdx.x >> 3;     // 8 x 32 store phase
    ushort4 o;
    o.x = f2bf(tile[kq * 4 + 0][n]);
    o.y = f2bf(tile[kq * 4 + 1][n]);
    o.z = f2bf(tile[kq * 4 + 2][n]);
    o.w = f2bf(tile[kq * 4 + 3][n]);
    *(ushort4*)(op + (size_t)(n0 + n) * K + k0 + kq * 4) = o;
}

// ----------------------------------------------------------- bf16 GEMM ------
// C[M][N] = A[M][K] * Bt[N][K]^T, 128x128 tile, BK=32, mfma 16x16x32 bf16.
// Depth-3 software pipeline, 4 LDS buffers, counted vmcnt fused into the
// barrier asm so hipcc cannot insert its own vmcnt(0) drain.
// R5: q+g and k+v merged into N=4608 launches (shared A panels).
template<bool EXPERT>
__global__ __launch_bounds__(256)
void gemm_bf16(const unsigned short* __restrict__ A,
               const unsigned short* __restrict__ Bt,
               float* __restrict__ C,
               const int* __restrict__ cnt, const int* __restrict__ basearr,
               int M, int K, int N)
{
    int e = EXPERT ? blockIdx.z : 0;
    int Mloc = M, base = 0;
    if (EXPERT) {
        Mloc = cnt[e]; base = basearr[e];
        if ((int)(blockIdx.x * 128) >= Mloc) return;
    }
    int m0 = blockIdx.x * 128, n0 = blockIdx.y * 128;
    const unsigned short* Ab = A + (size_t)base * K;
    const unsigned short* Bb = Bt + (size_t)e * (size_t)K * N;
    __shared__ unsigned short As[4][128 * 32];
    __shared__ unsigned short Bs[4][128 * 32];
    int tid = threadIdx.x;
    int lane = tid & 63, wave = tid >> 6;
    const unsigned short* ga[2];
    const unsigned short* gb[2];
    int lo[2];
#pragma unroll
    for (int j = 0; j < 2; ++j) {
        int flat = j * 256 + tid;
        int row = flat >> 2, sub = flat & 3;
        int ar = m0 + row; if (ar > Mloc - 1) ar = Mloc - 1;
        ga[j] = Ab + (size_t)ar * K + sub * 8;
        gb[j] = Bb + (size_t)(n0 + row) * K + sub * 8;
        lo[j] = flat * 8;
    }
    floatx4 acc[4][4];
#pragma unroll
    for (int i = 0; i < 4; ++i)
#pragma unroll
        for (int j = 0; j < 4; ++j) acc[i][j] = (floatx4){0.f, 0.f, 0.f, 0.f};

    int wm = (wave >> 1) * 64, wn = (wave & 1) * 64;
    int fr = lane & 15, kr = (lane >> 4) * 8;

    int nk = K >> 5;
    auto stage = [&](int buf, int t) {
        int k0 = t << 5;
        gl_lds16(ga[0] + k0, As[buf] + lo[0]);
        gl_lds16(gb[0] + k0, Bs[buf] + lo[0]);
        gl_lds16(ga[1] + k0, As[buf] + lo[1]);
        gl_lds16(gb[1] + k0, Bs[buf] + lo[1]);
    };
    stage(0, 0);
    stage(1, 1);
    stage(2, 2);
    int cur = 0;
    for (int t = 0; t < nk; ++t) {
        int nxt = (cur + 3) & 3;
        if (t + 3 < nk) stage(nxt, t + 3);
        int ahead = nk - 1 - t;
        if (ahead >= 3)      asm volatile("s_waitcnt vmcnt(12)\n\ts_barrier" ::: "memory");
        else if (ahead == 2) asm volatile("s_waitcnt vmcnt(8)\n\ts_barrier" ::: "memory");
        else if (ahead == 1) asm volatile("s_waitcnt vmcnt(4)\n\ts_barrier" ::: "memory");
        else                 asm volatile("s_waitcnt vmcnt(0)\n\ts_barrier" ::: "memory");
        bf16x8 af[4], bfr[4];
        const unsigned short* Ac = As[cur];
        const unsigned short* Bc = Bs[cur];
#pragma unroll
        for (int f = 0; f < 4; ++f) {
            af[f]  = *(const bf16x8*)(Ac + (size_t)(wm + f * 16 + fr) * 32 + kr);
            bfr[f] = *(const bf16x8*)(Bc + (size_t)(wn + f * 16 + fr) * 32 + kr);
        }
#pragma unroll
        for (int fm = 0; fm < 4; ++fm)
#pragma unroll
            for (int fn = 0; fn < 4; ++fn)
                acc[fm][fn] = __builtin_amdgcn_mfma_f32_16x16x32_bf16(af[fm], bfr[fn], acc[fm][fn], 0, 0, 0);
        asm volatile("s_waitcnt lgkmcnt(0)\n\ts_barrier" ::: "memory");
        cur = (cur + 1) & 3;
    }
    int rb = (lane >> 4) * 4;
#pragma unroll
    for (int fm = 0; fm < 4; ++fm) {
#pragma unroll
        for (int r = 0; r < 4; ++r) {
            int m = m0 + wm + fm * 16 + rb + r;
            if (m < Mloc) {
                float* cp = C + (size_t)(base + m) * N + n0 + wn + fr;
#pragma unroll
                for (int fn = 0; fn < 4; ++fn)
                    cp[fn * 16] = acc[fm][fn][r];
            }
        }
    }
}

// ------------------------------------------- beta / g small projections ----
__global__ void ba_kernel(const float* __restrict__ hidden,
                          const float* __restrict__ b_w, const float* __restrict__ a_w,
                          const float* __restrict__ A_log, const float* __restrict__ dt_bias,
                          const int* __restrict__ list, const int* __restrict__ cnt,
                          const int* __restrict__ basearr,
                          float* __restrict__ beta_c, float* __restrict__ g_c)
{
    int j = blockIdx.x, e = blockIdx.y;
    if (j >= cnt[e]) return;
    int gpos = basearr[e] + j;
    int tok = list[gpos];
    int lane = threadIdx.x;                      // 64
    const float* hr = hidden + (size_t)tok * Dm;
    float h[32];
#pragma unroll
    for (int i = 0; i < 32; ++i) h[i] = hr[lane + 64 * i];
    for (int c = 0; c < 12; ++c) {
        int col = c % 6;
        const float* W = ((c < 6) ? b_w : a_w) + (size_t)e * Dm * 6;
        float acc = 0.f;
#pragma unroll
        for (int i = 0; i < 32; ++i) acc += h[i] * W[(size_t)(lane + 64 * i) * 6 + col];
#pragma unroll
        for (int off = 1; off < 64; off <<= 1) acc += __shfl_xor(acc, off, 64);
        if (lane == 0) {
            if (c < 6) {
                beta_c[gpos * 6 + col] = 1.f / (1.f + expf(-acc));
            } else {
                float x = acc + dt_bias[col];
                float sp = (x > 20.f) ? x : log1pf(expf(x));
                g_c[gpos * 6 + col] = -expf(A_log[col]) * sp;
            }
        }
    }
}

// -------------------------------------- causal conv4 + silu (+ l2 norm) ----
// X rows at stride xstride (fused qg / kv buffers, cols 0..KD-1).
template<bool GATHER>
__global__ void conv_norm_kernel(const float* __restrict__ X, int xstride,
                                 const float* __restrict__ convw,
                                 const int* __restrict__ list, const int* __restrict__ cnt,
                                 const int* __restrict__ basearr,
                                 float* __restrict__ outb, float scale)
{
    int j = blockIdx.x, e = blockIdx.y, h = blockIdx.z;
    if (j >= cnt[e]) return;
    int base = basearr[e];
    int gpos = base + j;
    int c = h * DKk + threadIdx.x;               // 256 threads
    float acc = 0.f;
#pragma unroll
    for (int tau = 0; tau < 4; ++tau) {
        int jj = j - 3 + tau;
        if (jj >= 0) {
            const float* row = GATHER ? (X + (size_t)list[base + jj] * xstride)
                                      : (X + (size_t)(base + jj) * xstride);
            acc += row[c] * convw[c * 4 + tau];
        }
    }
    float y = acc / (1.f + expf(-acc));          // silu
    float v = y * y;
#pragma unroll
    for (int off = 1; off < 64; off <<= 1) v += __shfl_xor(v, off, 64);
    __shared__ float red[4];
    if ((threadIdx.x & 63) == 0) red[threadIdx.x >> 6] = v;
    __syncthreads();
    float total = red[0] + red[1] + red[2] + red[3];
    outb[(size_t)gpos * KD + c] = y * rsqrtf(total + 1e-6f) * scale;
}

// v-conv reads fused kv rows, cols KD..KD+VD-1.
__global__ void conv_v_kernel(const float* __restrict__ X,
                              const float* __restrict__ convw,
                              const int* __restrict__ cnt, const int* __restrict__ basearr,
                              float* __restrict__ outb)
{
    int j = blockIdx.x, e = blockIdx.y;
    if (j >= cnt[e]) return;
    int base = basearr[e];
    int gpos = base + j;
    int c = blockIdx.z * 256 + threadIdx.x;      // 12 * 256 = 3072
    float acc = 0.f;
#pragma unroll
    for (int tau = 0; tau < 4; ++tau) {
        int jj = j - 3 + tau;
        if (jj >= 0) acc += X[(size_t)(base + jj) * QGW + KD + c] * convw[c * 4 + tau];
    }
    outb[(size_t)gpos * VD + c] = acc / (1.f + expf(-acc));
}

// ------------------------------------------------ qk = q . k precompute ----
__global__ void qk_kernel(const float* __restrict__ qn, const float* __restrict__ kn,
                          float* __restrict__ qk_c)
{
    int gpos = blockIdx.x, h = blockIdx.y;
    int lane = threadIdx.x;                      // 64
    const float4* qp = (const float4*)(qn + (size_t)gpos * KD + h * DKk);
    const float4* kp = (const float4*)(kn + (size_t)gpos * KD + h * DKk);
    float4 a = qp[lane], b = kp[lane];
    float acc = a.x * b.x + a.y * b.y + a.z * b.z + a.w * b.w;
#pragma unroll
    for (int off = 1; off < 64; off <<= 1) acc += __shfl_xor(acc, off, 64);
    if (lane == 0) qk_c[(size_t)gpos * Hh + h] = acc;
}

// --------------------------------------------- gated delta rule (serial) ----
// EXACT R4 configuration (measured 266 us, VALUBusy 70%, VGPR 72, 0 bank
// conflicts): grid (16,H,E)=768 blocks = 3 blocks/CU single pass; thread =
// (kpart 0..7, vcol 0..31), 32 state floats. k/q staged in LDS via gl_lds16
// (double-buffered CH=4 chunks, counted vmcnt(2)); scalars chunk-prefetched;
// qk hoisted. R5's 16x16/1536-block split REGRESSED to 399 us: grid exceeded
// the launch_bounds(256,4) single-pass capacity (~4 blocks/CU) -> 2 dispatch
// passes (occupancy 37% = half of 75% theoretical), +1 shfl hop, +13MB fetch.
// Lesson: wall time = passes x per-block serial time; grid <= 1-pass capacity.
__global__ __launch_bounds__(256, 3)
void recurrence_kernel(const float* __restrict__ qn, const float* __restrict__ kn,
                       const float* __restrict__ vc,
                       const float* __restrict__ beta_c, const float* __restrict__ g_c,
                       const float* __restrict__ qk_c,
                       const int* __restrict__ cnt, const int* __restrict__ basearr,
                       float* __restrict__ o_c)
{
    int vb = blockIdx.x, h = blockIdx.y, e = blockIdx.z;
    int n = cnt[e], base = basearr[e];
    if (n <= 0) return;
    int tid = threadIdx.x;
    int kpart = tid & 7, vcol = tid >> 3;
    int v = vb * 32 + vcol;
    int wv = tid >> 6, lane = tid & 63;

    __shared__ float lk[2][CH][256];             // 8 KB
    __shared__ float lq[2][CH][256];             // 8 KB

    const float* kb = kn + (size_t)base * KD + h * DKk;
    const float* qb = qn + (size_t)base * KD + h * DKk;
    const float* vp = vc + (size_t)base * VD + h * DVv + v;
    const float* gp = g_c    + (size_t)base * Hh + h;
    const float* bp = beta_c + (size_t)base * Hh + h;
    const float* xp = qk_c   + (size_t)base * Hh + h;
    float* op = o_c + (size_t)base * VD + h * DVv + v;

    float4 s[8];
#pragma unroll
    for (int i = 0; i < 8; ++i) s[i] = make_float4(0.f, 0.f, 0.f, 0.f);

    int nch = (n + CH - 1) / CH;

    // wave wv stages row wv of the chunk: 1 k-row + 1 q-row = 2 vm insts/wave.
    auto stageKQ = [&](int buf, int c) {
        int jj = c * CH + wv; if (jj > n - 1) jj = n - 1;
        gl_lds16(kb + (size_t)jj * KD + lane * 4, &lk[buf][wv][lane * 4]);
        gl_lds16(qb + (size_t)jj * KD + lane * 4, &lq[buf][wv][lane * 4]);
    };

    float vA[CH], gA[CH], bA[CH], xA[CH];
    float vB[CH], gB[CH], bB[CH], xB[CH];

    auto loadScal = [&](float (&V)[CH], float (&G)[CH], float (&B)[CH], float (&X)[CH], int c) {
#pragma unroll
        for (int u = 0; u < CH; ++u) {
            int jj = c * CH + u; if (jj > n - 1) jj = n - 1;
            V[u] = vp[(size_t)jj * VD];
            G[u] = gp[(size_t)jj * Hh];
            B[u] = bp[(size_t)jj * Hh];
            X[u] = xp[(size_t)jj * Hh];
        }
    };

    auto computeChunk = [&](const float (&Lk)[CH][256], const float (&Lq)[CH][256],
                            const float (&V)[CH], const float (&G)[CH],
                            const float (&B)[CH], const float (&X)[CH], int c) {
#pragma unroll
        for (int u = 0; u < CH; ++u) {
            // lane owns k-dims {kpart*4 + j + i*32}: conflict-free banks.
            const float* Lku = &Lk[u][kpart * 4];
            const float* Lqu = &Lq[u][kpart * 4];
            float4 pa0 = make_float4(0.f,0.f,0.f,0.f), pa1 = make_float4(0.f,0.f,0.f,0.f);
            float4 ra0 = make_float4(0.f,0.f,0.f,0.f), ra1 = make_float4(0.f,0.f,0.f,0.f);
            float4 kk[8];
#pragma unroll
            for (int i = 0; i < 8; ++i) {
                kk[i] = *(const float4*)(Lku + i * 32);
                float4 qq = *(const float4*)(Lqu + i * 32);
                float4& pa = (i & 1) ? pa1 : pa0;
                float4& ra = (i & 1) ? ra1 : ra0;
                pa.x = fmaf(kk[i].x, s[i].x, pa.x); pa.y = fmaf(kk[i].y, s[i].y, pa.y);
                pa.z = fmaf(kk[i].z, s[i].z, pa.z); pa.w = fmaf(kk[i].w, s[i].w, pa.w);
                ra.x = fmaf(qq.x, s[i].x, ra.x); ra.y = fmaf(qq.y, s[i].y, ra.y);
                ra.z = fmaf(qq.z, s[i].z, ra.z); ra.w = fmaf(qq.w, s[i].w, ra.w);
            }
            float p = ((pa0.x + pa1.x) + (pa0.y + pa1.y)) + ((pa0.z + pa1.z) + (pa0.w + pa1.w));
            float r = ((ra0.x + ra1.x) + (ra0.y + ra1.y)) + ((ra0.z + ra1.z) + (ra0.w + ra1.w));
#pragma unroll
            for (int m = 1; m < 8; m <<= 1) {
                p += __shfl_xor(p, m, 64);
                r += __shfl_xor(r, m, 64);
            }
            float eg = __expf(G[u]);
            float delta = (V[u] - p * eg) * B[u];
            float out = fmaf(X[u], delta, eg * r);
#pragma unroll
            for (int i = 0; i < 8; ++i) {
                s[i].x = fmaf(eg, s[i].x, kk[i].x * delta);
                s[i].y = fmaf(eg, s[i].y, kk[i].y * delta);
                s[i].z = fmaf(eg, s[i].z, kk[i].z * delta);
                s[i].w = fmaf(eg, s[i].w, kk[i].w * delta);
            }
            int j = c * CH + u;
            if (kpart == 0 && j < n) op[(size_t)j * VD] = out;
        }
    };

    // prologue: chunk0 kq + scalars, chunk1 kq in flight.
    stageKQ(0, 0);
    loadScal(vA, gA, bA, xA, 0);
    stageKQ(1, 1);
    asm volatile("s_waitcnt vmcnt(2)\n\ts_barrier" ::: "memory");

    for (int c = 0; c < nch; c += 2) {
        loadScal(vB, gB, bB, xB, c + 1);         // clamped; uniform vm counts
        computeChunk(lk[0], lq[0], vA, gA, bA, xA, c);
        __syncthreads();                          // all waves done reading lk[0]
        stageKQ(0, c + 2);                        // clamped (always 2 insts)
        asm volatile("s_waitcnt vmcnt(2)\n\ts_barrier" ::: "memory");
        if (c + 1 >= nch) break;
        loadScal(vA, gA, bA, xA, c + 2);
        computeChunk(lk[1], lq[1], vB, gB, bB, xB, c + 1);
        __syncthreads();
        stageKQ(1, c + 3);
        asm volatile("s_waitcnt vmcnt(2)\n\ts_barrier" ::: "memory");
    }
    asm volatile("s_waitcnt vmcnt(0)" ::: "memory");   // drain tail staging
}

// ------------------------------- combine + gated RMSNorm (swish gate) -------
// gate read from the fused qg buffer (cols KD..KD+VD-1 of row t).
__global__ void combine_kernel(const float* __restrict__ o_c, const float* __restrict__ qg,
                               const float* __restrict__ norm_w,
                               const int* __restrict__ posg, const float* __restrict__ w01,
                               unsigned short* __restrict__ ocg)
{
    int t = blockIdx.x, h = blockIdx.y;
    int p0 = posg[2 * t], p1 = posg[2 * t + 1];
    float w0 = w01[2 * t], w1 = w01[2 * t + 1];
    int v0 = threadIdx.x, v1 = threadIdx.x + 256;
    size_t r0 = (size_t)p0 * VD + h * DVv, r1 = (size_t)p1 * VD + h * DVv;
    float a  = w0 * o_c[r0 + v0] + w1 * o_c[r1 + v0];
    float b2 = w0 * o_c[r0 + v1] + w1 * o_c[r1 + v1];
    float val = a * a + b2 * b2;
#pragma unroll
    for (int off = 1; off < 64; off <<= 1) val += __shfl_xor(val, off, 64);
    __shared__ float red[4];
    if ((threadIdx.x & 63) == 0) red[threadIdx.x >> 6] = val;
    __syncthreads();
    float total = red[0] + red[1] + red[2] + red[3];
    float rms = rsqrtf(total / 512.f + 1e-5f);
    size_t og = (size_t)t * VD + h * DVv;
    size_t gq = (size_t)t * QGW + KD + h * DVv;
    float g0 = qg[gq + v0], g1 = qg[gq + v1];
    ocg[og + v0] = f2bf(a  * rms * norm_w[v0] * g0 / (1.f + expf(-g0)));
    ocg[og + v1] = f2bf(b2 * rms * norm_w[v1] * g1 / (1.f + expf(-g1)));
}

// ------------------------------------------------------------------ host ----
extern "C" void kernel_launch(void* const* d_in, const int* in_sizes, int n_in,
                              void* d_out, int out_size, void* d_ws, size_t ws_size,
                              hipStream_t stream)
{
    const float* hidden   = (const float*)d_in[0];
    const float* q_w      = (const float*)d_in[1];
    const float* gate_w   = (const float*)d_in[2];
    const float* k_w      = (const float*)d_in[3];
    const float* v_w      = (const float*)d_in[4];
    const float* b_w      = (const float*)d_in[5];
    const float* a_w      = (const float*)d_in[6];
    const float* A_log    = (const float*)d_in[7];
    const float* dt_bias  = (const float*)d_in[8];
    const float* q_conv_w = (const float*)d_in[9];
    const float* k_conv_w = (const float*)d_in[10];
    const float* v_conv_w = (const float*)d_in[11];
    const float* g_w      = (const float*)d_in[12];
    const float* norm_w   = (const float*)d_in[13];
    const float* o_w      = (const float*)d_in[14];
    float* outp = (float*)d_out;

    float* f = (float*)d_ws;
    size_t off = 0;
    auto alloc = [&](size_t n) { float* p = f + off; off += (n + 3) & ~(size_t)3; return p; };
    float* qg     = alloc((size_t)1024 * QGW);    // [t][0:1536]=qh, [1536:4608]=gg
    float* kvraw  = alloc((size_t)2048 * QGW);    // [slot][0:1536]=kraw, [1536:4608]=vraw
    float* qn     = alloc((size_t)2048 * 1536);
    float* kn     = alloc((size_t)2048 * 1536);
    float* vconv  = alloc((size_t)2048 * 3072);
    float* o_c    = alloc((size_t)2048 * 3072);
    float* beta_c = alloc(2048 * 6);
    float* g_c    = alloc(2048 * 6);
    float* qk_c   = alloc(2048 * 6);
    float* w01f   = alloc(2048);

    unsigned short* u = (unsigned short*)(f + off);
    size_t uoff = 0;
    auto ualloc = [&](size_t n) { unsigned short* p = u + uoff; uoff += (n + 7) & ~(size_t)7; return p; };
    unsigned short* hidden_bf = ualloc((size_t)1024 * 2048);
    unsigned short* xe_c      = ualloc((size_t)2048 * 2048);
    unsigned short* ocg       = ualloc((size_t)1024 * 3072);
    unsigned short* qg_wT     = ualloc((size_t)QGW * 2048);       // q rows 0-1535, g rows 1536-4607
    unsigned short* kv_wT     = ualloc((size_t)8 * QGW * 2048);   // per e: k rows 0-1535, v rows 1536-4607
    unsigned short* o_wT      = ualloc((size_t)3072 * 2048);

    int* ib      = (int*)(u + uoff);
    int* sel01   = ib;
    int* list_c  = ib + 2048;
    int* posg    = ib + 4096;
    int* cnt     = ib + 6144;
    int* basearr = ib + 6152;

    const size_t EST = (size_t)2048 * QGW;       // expert stride in fused kv_wT

    router_kernel<<<1024, 64, 0, stream>>>(hidden, gate_w, sel01, w01f);
    dispatch_kernel<<<1, 1024, 0, stream>>>(sel01, list_c, posg, cnt, basearr);

    cast_bf16_kernel<<<2048, 256, 0, stream>>>(hidden, hidden_bf);
    gather_cast_kernel<<<2048, 256, 0, stream>>>(hidden, list_c, xe_c);
    transpose_cast_kernel<<<dim3(64, 48, 1), 256, 0, stream>>>(q_w, qg_wT, 2048, 1536, 0);
    transpose_cast_kernel<<<dim3(64, 96, 1), 256, 0, stream>>>(g_w, qg_wT + (size_t)1536 * 2048, 2048, 3072, 0);
    transpose_cast_kernel<<<dim3(64, 48, 8), 256, 0, stream>>>(k_w, kv_wT, 2048, 1536, EST);
    transpose_cast_kernel<<<dim3(64, 96, 8), 256, 0, stream>>>(v_w, kv_wT + (size_t)1536 * 2048, 2048, 3072, EST);
    transpose_cast_kernel<<<dim3(96, 64, 1), 256, 0, stream>>>(o_w, o_wT, 3072, 2048, 0);

    gemm_bf16<false><<<dim3(8, 36), 256, 0, stream>>>(hidden_bf, qg_wT, qg, nullptr, nullptr, 1024, 2048, QGW);
    gemm_bf16<true ><<<dim3(8, 36, 8), 256, 0, stream>>>(xe_c, kv_wT, kvraw, cnt, basearr, 0, 2048, QGW);

    ba_kernel<<<dim3(1024, 8), 64, 0, stream>>>(hidden, b_w, a_w, A_log, dt_bias,
                                                list_c, cnt, basearr, beta_c, g_c);

    conv_norm_kernel<true ><<<dim3(1024, 8, 6), 256, 0, stream>>>(qg,    QGW, q_conv_w, list_c, cnt, basearr, qn, 0.0625f);
    conv_norm_kernel<false><<<dim3(1024, 8, 6), 256, 0, stream>>>(kvraw, QGW, k_conv_w, list_c, cnt, basearr, kn, 1.0f);
    conv_v_kernel<<<dim3(1024, 8, 12), 256, 0, stream>>>(kvraw, v_conv_w, cnt, basearr, vconv);

    qk_kernel<<<dim3(2048, 6), 64, 0, stream>>>(qn, kn, qk_c);

    recurrence_kernel<<<dim3(16, 6, 8), 256, 0, stream>>>(qn, kn, vconv, beta_c, g_c, qk_c,
                                                          cnt, basearr, o_c);

    combine_kernel<<<dim3(1024, 6), 256, 0, stream>>>(o_c, qg, norm_w, posg, w01f, ocg);
    gemm_bf16<false><<<dim3(8, 16), 256, 0, stream>>>(ocg, o_wT, outp, nullptr, nullptr, 1024, 3072, 2048);
}

// Round 8
// 1183.887 us; speedup vs baseline: 1.1378x; 1.0414x over previous
//
#include <hip/hip_runtime.h>
#include <math.h>

#define Dm    2048
#define Hh    6
#define DKk   256
#define DVv   512
#define KD    1536
#define VD    3072
#define QGW   4608
#define CH    4

typedef __attribute__((ext_vector_type(8))) __bf16 bf16x8;
typedef __attribute__((ext_vector_type(4))) float floatx4;

__device__ __forceinline__ unsigned short f2bf(float f) {
    unsigned int u = __float_as_uint(f);
    u = (u + 0x7fffu + ((u >> 16) & 1u)) >> 16;
    return (unsigned short)u;
}

__device__ __forceinline__ void gl_lds16(const void* g, void* l) {
    __builtin_amdgcn_global_load_lds((const __attribute__((address_space(1))) void*)g,
                                     (__attribute__((address_space(3))) void*)l, 16, 0, 0);
}

// ---------------------------------------------------------------- router ----
__global__ void router_kernel(const float* __restrict__ hidden,
                              const float* __restrict__ gate_w,
                              int* __restrict__ sel01, float* __restrict__ w01)
{
    int t = blockIdx.x;
    int lane = threadIdx.x;                      // 64 threads
    const float* hr = hidden + (size_t)t * Dm;
    float h[32];
#pragma unroll
    for (int i = 0; i < 32; ++i) h[i] = hr[lane + 64 * i];
    float logit[8];
#pragma unroll
    for (int e = 0; e < 8; ++e) {
        float acc = 0.f;
#pragma unroll
        for (int i = 0; i < 32; ++i) acc += h[i] * gate_w[(size_t)(lane + 64 * i) * 8 + e];
#pragma unroll
        for (int off = 1; off < 64; off <<= 1) acc += __shfl_xor(acc, off, 64);
        logit[e] = acc;
    }
    if (lane == 0) {
        int i0 = 0;
#pragma unroll
        for (int e = 1; e < 8; ++e) if (logit[e] > logit[i0]) i0 = e;
        int i1 = (i0 == 0) ? 1 : 0;
#pragma unroll
        for (int e = 0; e < 8; ++e) if (e != i0 && logit[e] > logit[i1]) i1 = e;
        float w0 = 1.f / (1.f + expf(logit[i1] - logit[i0]));
        sel01[2 * t] = i0; sel01[2 * t + 1] = i1;
        w01[2 * t] = w0;   w01[2 * t + 1] = 1.f - w0;
    }
}

// -------------------------------------------------------------- dispatch ----
__global__ void dispatch_kernel(const int* __restrict__ sel01,
                                int* __restrict__ list_c, int* __restrict__ posg,
                                int* __restrict__ cnt, int* __restrict__ basearr)
{
    __shared__ int wbase[16];
    __shared__ int sbase;
    int t = threadIdx.x;
    int lane = t & 63, w = t >> 6;
    int s0 = sel01[2 * t], s1 = sel01[2 * t + 1];
    if (t == 0) sbase = 0;
    __syncthreads();
    for (int e = 0; e < 8; ++e) {
        int flag  = (s0 == e || s1 == e) ? 1 : 0;
        int kslot = (s0 == e) ? 0 : 1;
        unsigned long long m = __ballot(flag);
        int lpre = __popcll(m & ((1ull << lane) - 1ull));
        if (lane == 0) wbase[w] = __popcll(m);
        __syncthreads();
        if (t == 0) {
            int run = sbase;
            basearr[e] = run;
            for (int i = 0; i < 16; ++i) { int tv = wbase[i]; wbase[i] = run; run += tv; }
            cnt[e] = run - sbase;
            sbase = run;
        }
        __syncthreads();
        if (flag) {
            int pos = wbase[w] + lpre;
            list_c[pos] = t;
            posg[2 * t + kslot] = pos;
        }
        __syncthreads();
    }
}

// ------------------------------------------------------------ bf16 casts ----
__global__ void cast_bf16_kernel(const float* __restrict__ x, unsigned short* __restrict__ y)
{
    int i = (blockIdx.x * 256 + threadIdx.x) * 4;
    float4 a = *(const float4*)(x + i);
    ushort4 o;
    o.x = f2bf(a.x); o.y = f2bf(a.y); o.z = f2bf(a.z); o.w = f2bf(a.w);
    *(ushort4*)(y + i) = o;
}

__global__ void gather_cast_kernel(const float* __restrict__ hidden, const int* __restrict__ list,
                                   unsigned short* __restrict__ xe)
{
    int slot = blockIdx.x;
    int tok = list[slot];
    const float* src = hidden + (size_t)tok * Dm;
    unsigned short* dst = xe + (size_t)slot * Dm;
    int c = threadIdx.x * 8;
    float4 a = *(const float4*)(src + c);
    float4 b = *(const float4*)(src + c + 4);
    ushort4 o1, o2;
    o1.x = f2bf(a.x); o1.y = f2bf(a.y); o1.z = f2bf(a.z); o1.w = f2bf(a.w);
    o2.x = f2bf(b.x); o2.y = f2bf(b.y); o2.z = f2bf(b.z); o2.w = f2bf(b.w);
    *(ushort4*)(dst + c) = o1;
    *(ushort4*)(dst + c + 4) = o2;
}

// fp32 [b][K][N] -> bf16 [b][N][K] at expert stride estride (fused buffers).
// R6: write phase vectorized (ushort4 per thread).
__global__ void transpose_cast_kernel(const float* __restrict__ in, unsigned short* __restrict__ out,
                                      int K, int N, size_t estride)
{
    __shared__ float tile[32][33];
    int b = blockIdx.z;
    int k0 = blockIdx.x * 32, n0 = blockIdx.y * 32;
    const float* ip = in + (size_t)b * K * N;
    unsigned short* op = out + (size_t)b * estride;
    int tx = threadIdx.x & 31, ty = threadIdx.x >> 5;   // 32 x 8 load phase
#pragma unroll
    for (int i = 0; i < 4; ++i)
        tile[ty + i * 8][tx] = ip[(size_t)(k0 + ty + i * 8) * N + n0 + tx];
    __syncthreads();
    int kq = threadIdx.x & 7, n = threadIdx.x >> 3;     // 8 x 32 store phase
    ushort4 o;
    o.x = f2bf(tile[kq * 4 + 0][n]);
    o.y = f2bf(tile[kq * 4 + 1][n]);
    o.z = f2bf(tile[kq * 4 + 2][n]);
    o.w = f2bf(tile[kq * 4 + 3][n]);
    *(ushort4*)(op + (size_t)(n0 + n) * K + k0 + kq * 4) = o;
}

// ----------------------------------------------------------- bf16 GEMM ------
// C[M][N] = A[M][K] * Bt[N][K]^T, 128x128 tile, BK=32, mfma 16x16x32 bf16.
// R7 counters (kv expert GEMM, 64KiB/4buf): MfmaUtil 6%, Occupancy 5.6%,
// 750 GB/s, 5.6M LDS bank conflicts -> latency-bound: 64KiB LDS caps 2
// blocks/CU, depth-3 leaves only ~1.5KB/CU outstanding vs ~500-900cyc L3/HBM
// latency. R8 fixes:
//  (a) EXPERT path (576 active blocks): 2-buffer depth-2 = 32KiB LDS ->
//      5 blocks/CU, 20 waves/CU; TLP does the hiding. vmcnt(4/0) counted.
//      Non-expert grids (~1 block/CU, no TLP available) keep 4-buf depth-3.
//  (b) XOR-swizzle (T2, rule #21): fragment read (row*64B + q*16B) had lanes
//      fr=0..15 on a 64B row stride = 8-way conflict per ds_read_b128.
//      Fix: linear gl_lds16 dest + pre-swizzled GLOBAL source slot
//      sub^((row>>1)&3) + same XOR on the read slot -> 2-way max (free).
template<bool EXPERT>
__global__ __launch_bounds__(256)
void gemm_bf16(const unsigned short* __restrict__ A,
               const unsigned short* __restrict__ Bt,
               float* __restrict__ C,
               const int* __restrict__ cnt, const int* __restrict__ basearr,
               int M, int K, int N)
{
    constexpr int NBUF = EXPERT ? 2 : 4;
    int e = EXPERT ? blockIdx.z : 0;
    int Mloc = M, base = 0;
    if (EXPERT) {
        Mloc = cnt[e]; base = basearr[e];
        if ((int)(blockIdx.x * 128) >= Mloc) return;
    }
    int m0 = blockIdx.x * 128, n0 = blockIdx.y * 128;
    const unsigned short* Ab = A + (size_t)base * K;
    const unsigned short* Bb = Bt + (size_t)e * (size_t)K * N;
    __shared__ unsigned short As[NBUF][128 * 32];
    __shared__ unsigned short Bs[NBUF][128 * 32];
    int tid = threadIdx.x;
    int lane = tid & 63, wave = tid >> 6;
    const unsigned short* ga[2];
    const unsigned short* gb[2];
    int lo[2];
#pragma unroll
    for (int j = 0; j < 2; ++j) {
        int flat = j * 256 + tid;
        int row = flat >> 2, sub = flat & 3;
        int subs = sub ^ ((row >> 1) & 3);       // pre-swizzled source slot
        int ar = m0 + row; if (ar > Mloc - 1) ar = Mloc - 1;
        ga[j] = Ab + (size_t)ar * K + subs * 8;
        gb[j] = Bb + (size_t)(n0 + row) * K + subs * 8;
        lo[j] = flat * 8;                        // linear LDS dest
    }
    floatx4 acc[4][4];
#pragma unroll
    for (int i = 0; i < 4; ++i)
#pragma unroll
        for (int j = 0; j < 4; ++j) acc[i][j] = (floatx4){0.f, 0.f, 0.f, 0.f};

    int wm = (wave >> 1) * 64, wn = (wave & 1) * 64;
    int fr = lane & 15, q = lane >> 4;
    int qs = q ^ ((fr >> 1) & 3);                // read slot after swizzle
                                                 // (row = 16-mult + fr -> (row>>1)&3 = (fr>>1)&3)
    int nk = K >> 5;
    auto stage = [&](int buf, int t) {
        int k0 = t << 5;
        gl_lds16(ga[0] + k0, As[buf] + lo[0]);
        gl_lds16(gb[0] + k0, Bs[buf] + lo[0]);
        gl_lds16(ga[1] + k0, As[buf] + lo[1]);
        gl_lds16(gb[1] + k0, Bs[buf] + lo[1]);
    };
#pragma unroll
    for (int b = 0; b < NBUF - 1; ++b) stage(b, b);
    int cur = 0;
    for (int t = 0; t < nk; ++t) {
        int nxt = cur + (NBUF - 1); if (nxt >= NBUF) nxt -= NBUF;
        if (t + NBUF - 1 < nk) stage(nxt, t + NBUF - 1);
        int ahead = nk - 1 - t;
        if constexpr (EXPERT) {
            if (ahead >= 1)      asm volatile("s_waitcnt vmcnt(4)\n\ts_barrier" ::: "memory");
            else                 asm volatile("s_waitcnt vmcnt(0)\n\ts_barrier" ::: "memory");
        } else {
            if (ahead >= 3)      asm volatile("s_waitcnt vmcnt(12)\n\ts_barrier" ::: "memory");
            else if (ahead == 2) asm volatile("s_waitcnt vmcnt(8)\n\ts_barrier" ::: "memory");
            else if (ahead == 1) asm volatile("s_waitcnt vmcnt(4)\n\ts_barrier" ::: "memory");
            else                 asm volatile("s_waitcnt vmcnt(0)\n\ts_barrier" ::: "memory");
        }
        bf16x8 af[4], bfr[4];
        const unsigned short* Ac = As[cur];
        const unsigned short* Bc = Bs[cur];
#pragma unroll
        for (int f = 0; f < 4; ++f) {
            af[f]  = *(const bf16x8*)(Ac + (size_t)(wm + f * 16 + fr) * 32 + qs * 8);
            bfr[f] = *(const bf16x8*)(Bc + (size_t)(wn + f * 16 + fr) * 32 + qs * 8);
        }
#pragma unroll
        for (int fm = 0; fm < 4; ++fm)
#pragma unroll
            for (int fn = 0; fn < 4; ++fn)
                acc[fm][fn] = __builtin_amdgcn_mfma_f32_16x16x32_bf16(af[fm], bfr[fn], acc[fm][fn], 0, 0, 0);
        asm volatile("s_waitcnt lgkmcnt(0)\n\ts_barrier" ::: "memory");
        cur = cur + 1 == NBUF ? 0 : cur + 1;
    }
    int rb = q * 4;
#pragma unroll
    for (int fm = 0; fm < 4; ++fm) {
#pragma unroll
        for (int r = 0; r < 4; ++r) {
            int m = m0 + wm + fm * 16 + rb + r;
            if (m < Mloc) {
                float* cp = C + (size_t)(base + m) * N + n0 + wn + fr;
#pragma unroll
                for (int fn = 0; fn < 4; ++fn)
                    cp[fn * 16] = acc[fm][fn][r];
            }
        }
    }
}

// ------------------------------------------- beta / g small projections ----
__global__ void ba_kernel(const float* __restrict__ hidden,
                          const float* __restrict__ b_w, const float* __restrict__ a_w,
                          const float* __restrict__ A_log, const float* __restrict__ dt_bias,
                          const int* __restrict__ list, const int* __restrict__ cnt,
                          const int* __restrict__ basearr,
                          float* __restrict__ beta_c, float* __restrict__ g_c)
{
    int j = blockIdx.x, e = blockIdx.y;
    if (j >= cnt[e]) return;
    int gpos = basearr[e] + j;
    int tok = list[gpos];
    int lane = threadIdx.x;                      // 64
    const float* hr = hidden + (size_t)tok * Dm;
    float h[32];
#pragma unroll
    for (int i = 0; i < 32; ++i) h[i] = hr[lane + 64 * i];
    for (int c = 0; c < 12; ++c) {
        int col = c % 6;
        const float* W = ((c < 6) ? b_w : a_w) + (size_t)e * Dm * 6;
        float acc = 0.f;
#pragma unroll
        for (int i = 0; i < 32; ++i) acc += h[i] * W[(size_t)(lane + 64 * i) * 6 + col];
#pragma unroll
        for (int off = 1; off < 64; off <<= 1) acc += __shfl_xor(acc, off, 64);
        if (lane == 0) {
            if (c < 6) {
                beta_c[gpos * 6 + col] = 1.f / (1.f + expf(-acc));
            } else {
                float x = acc + dt_bias[col];
                float sp = (x > 20.f) ? x : log1pf(expf(x));
                g_c[gpos * 6 + col] = -expf(A_log[col]) * sp;
            }
        }
    }
}

// -------------------------------------- causal conv4 + silu (+ l2 norm) ----
template<bool GATHER>
__global__ void conv_norm_kernel(const float* __restrict__ X, int xstride,
                                 const float* __restrict__ convw,
                                 const int* __restrict__ list, const int* __restrict__ cnt,
                                 const int* __restrict__ basearr,
                                 float* __restrict__ outb, float scale)
{
    int j = blockIdx.x, e = blockIdx.y, h = blockIdx.z;
    if (j >= cnt[e]) return;
    int base = basearr[e];
    int gpos = base + j;
    int c = h * DKk + threadIdx.x;               // 256 threads
    float acc = 0.f;
#pragma unroll
    for (int tau = 0; tau < 4; ++tau) {
        int jj = j - 3 + tau;
        if (jj >= 0) {
            const float* row = GATHER ? (X + (size_t)list[base + jj] * xstride)
                                      : (X + (size_t)(base + jj) * xstride);
            acc += row[c] * convw[c * 4 + tau];
        }
    }
    float y = acc / (1.f + expf(-acc));          // silu
    float v = y * y;
#pragma unroll
    for (int off = 1; off < 64; off <<= 1) v += __shfl_xor(v, off, 64);
    __shared__ float red[4];
    if ((threadIdx.x & 63) == 0) red[threadIdx.x >> 6] = v;
    __syncthreads();
    float total = red[0] + red[1] + red[2] + red[3];
    outb[(size_t)gpos * KD + c] = y * rsqrtf(total + 1e-6f) * scale;
}

// v-conv reads fused kv rows, cols KD..KD+VD-1.
__global__ void conv_v_kernel(const float* __restrict__ X,
                              const float* __restrict__ convw,
                              const int* __restrict__ cnt, const int* __restrict__ basearr,
                              float* __restrict__ outb)
{
    int j = blockIdx.x, e = blockIdx.y;
    if (j >= cnt[e]) return;
    int base = basearr[e];
    int gpos = base + j;
    int c = blockIdx.z * 256 + threadIdx.x;      // 12 * 256 = 3072
    float acc = 0.f;
#pragma unroll
    for (int tau = 0; tau < 4; ++tau) {
        int jj = j - 3 + tau;
        if (jj >= 0) acc += X[(size_t)(base + jj) * QGW + KD + c] * convw[c * 4 + tau];
    }
    outb[(size_t)gpos * VD + c] = acc / (1.f + expf(-acc));
}

// ------------------------------------------------ qk = q . k precompute ----
__global__ void qk_kernel(const float* __restrict__ qn, const float* __restrict__ kn,
                          float* __restrict__ qk_c)
{
    int gpos = blockIdx.x, h = blockIdx.y;
    int lane = threadIdx.x;                      // 64
    const float4* qp = (const float4*)(qn + (size_t)gpos * KD + h * DKk);
    const float4* kp = (const float4*)(kn + (size_t)gpos * KD + h * DKk);
    float4 a = qp[lane], b = kp[lane];
    float acc = a.x * b.x + a.y * b.y + a.z * b.z + a.w * b.w;
#pragma unroll
    for (int off = 1; off < 64; off <<= 1) acc += __shfl_xor(acc, off, 64);
    if (lane == 0) qk_c[(size_t)gpos * Hh + h] = acc;
}

// --------------------------------------------- gated delta rule (serial) ----
// EXACT R4 configuration (measured 266 us): grid (16,H,E)=768 blocks =
// 3 blocks/CU single pass; thread = (kpart 0..7, vcol 0..31). k/q staged in
// LDS via gl_lds16 (double-buffered CH=4 chunks, counted vmcnt(2)); scalars
// chunk-prefetched; qk hoisted. (R5 finer split regressed: 2 dispatch passes.)
__global__ __launch_bounds__(256, 3)
void recurrence_kernel(const float* __restrict__ qn, const float* __restrict__ kn,
                       const float* __restrict__ vc,
                       const float* __restrict__ beta_c, const float* __restrict__ g_c,
                       const float* __restrict__ qk_c,
                       const int* __restrict__ cnt, const int* __restrict__ basearr,
                       float* __restrict__ o_c)
{
    int vb = blockIdx.x, h = blockIdx.y, e = blockIdx.z;
    int n = cnt[e], base = basearr[e];
    if (n <= 0) return;
    int tid = threadIdx.x;
    int kpart = tid & 7, vcol = tid >> 3;
    int v = vb * 32 + vcol;
    int wv = tid >> 6, lane = tid & 63;

    __shared__ float lk[2][CH][256];             // 8 KB
    __shared__ float lq[2][CH][256];             // 8 KB

    const float* kb = kn + (size_t)base * KD + h * DKk;
    const float* qb = qn + (size_t)base * KD + h * DKk;
    const float* vp = vc + (size_t)base * VD + h * DVv + v;
    const float* gp = g_c    + (size_t)base * Hh + h;
    const float* bp = beta_c + (size_t)base * Hh + h;
    const float* xp = qk_c   + (size_t)base * Hh + h;
    float* op = o_c + (size_t)base * VD + h * DVv + v;

    float4 s[8];
#pragma unroll
    for (int i = 0; i < 8; ++i) s[i] = make_float4(0.f, 0.f, 0.f, 0.f);

    int nch = (n + CH - 1) / CH;

    auto stageKQ = [&](int buf, int c) {
        int jj = c * CH + wv; if (jj > n - 1) jj = n - 1;
        gl_lds16(kb + (size_t)jj * KD + lane * 4, &lk[buf][wv][lane * 4]);
        gl_lds16(qb + (size_t)jj * KD + lane * 4, &lq[buf][wv][lane * 4]);
    };

    float vA[CH], gA[CH], bA[CH], xA[CH];
    float vB[CH], gB[CH], bB[CH], xB[CH];

    auto loadScal = [&](float (&V)[CH], float (&G)[CH], float (&B)[CH], float (&X)[CH], int c) {
#pragma unroll
        for (int u = 0; u < CH; ++u) {
            int jj = c * CH + u; if (jj > n - 1) jj = n - 1;
            V[u] = vp[(size_t)jj * VD];
            G[u] = gp[(size_t)jj * Hh];
            B[u] = bp[(size_t)jj * Hh];
            X[u] = xp[(size_t)jj * Hh];
        }
    };

    auto computeChunk = [&](const float (&Lk)[CH][256], const float (&Lq)[CH][256],
                            const float (&V)[CH], const float (&G)[CH],
                            const float (&B)[CH], const float (&X)[CH], int c) {
#pragma unroll
        for (int u = 0; u < CH; ++u) {
            const float* Lku = &Lk[u][kpart * 4];
            const float* Lqu = &Lq[u][kpart * 4];
            float4 pa0 = make_float4(0.f,0.f,0.f,0.f), pa1 = make_float4(0.f,0.f,0.f,0.f);
            float4 ra0 = make_float4(0.f,0.f,0.f,0.f), ra1 = make_float4(0.f,0.f,0.f,0.f);
            float4 kk[8];
#pragma unroll
            for (int i = 0; i < 8; ++i) {
                kk[i] = *(const float4*)(Lku + i * 32);
                float4 qq = *(const float4*)(Lqu + i * 32);
                float4& pa = (i & 1) ? pa1 : pa0;
                float4& ra = (i & 1) ? ra1 : ra0;
                pa.x = fmaf(kk[i].x, s[i].x, pa.x); pa.y = fmaf(kk[i].y, s[i].y, pa.y);
                pa.z = fmaf(kk[i].z, s[i].z, pa.z); pa.w = fmaf(kk[i].w, s[i].w, pa.w);
                ra.x = fmaf(qq.x, s[i].x, ra.x); ra.y = fmaf(qq.y, s[i].y, ra.y);
                ra.z = fmaf(qq.z, s[i].z, ra.z); ra.w = fmaf(qq.w, s[i].w, ra.w);
            }
            float p = ((pa0.x + pa1.x) + (pa0.y + pa1.y)) + ((pa0.z + pa1.z) + (pa0.w + pa1.w));
            float r = ((ra0.x + ra1.x) + (ra0.y + ra1.y)) + ((ra0.z + ra1.z) + (ra0.w + ra1.w));
#pragma unroll
            for (int m = 1; m < 8; m <<= 1) {
                p += __shfl_xor(p, m, 64);
                r += __shfl_xor(r, m, 64);
            }
            float eg = __expf(G[u]);
            float delta = (V[u] - p * eg) * B[u];
            float out = fmaf(X[u], delta, eg * r);
#pragma unroll
            for (int i = 0; i < 8; ++i) {
                s[i].x = fmaf(eg, s[i].x, kk[i].x * delta);
                s[i].y = fmaf(eg, s[i].y, kk[i].y * delta);
                s[i].z = fmaf(eg, s[i].z, kk[i].z * delta);
                s[i].w = fmaf(eg, s[i].w, kk[i].w * delta);
            }
            int j = c * CH + u;
            if (kpart == 0 && j < n) op[(size_t)j * VD] = out;
        }
    };

    stageKQ(0, 0);
    loadScal(vA, gA, bA, xA, 0);
    stageKQ(1, 1);
    asm volatile("s_waitcnt vmcnt(2)\n\ts_barrier" ::: "memory");

    for (int c = 0; c < nch; c += 2) {
        loadScal(vB, gB, bB, xB, c + 1);
        computeChunk(lk[0], lq[0], vA, gA, bA, xA, c);
        __syncthreads();
        stageKQ(0, c + 2);
        asm volatile("s_waitcnt vmcnt(2)\n\ts_barrier" ::: "memory");
        if (c + 1 >= nch) break;
        loadScal(vA, gA, bA, xA, c + 2);
        computeChunk(lk[1], lq[1], vB, gB, bB, xB, c + 1);
        __syncthreads();
        stageKQ(1, c + 3);
        asm volatile("s_waitcnt vmcnt(2)\n\ts_barrier" ::: "memory");
    }
    asm volatile("s_waitcnt vmcnt(0)" ::: "memory");
}

// ------------------------------- combine + gated RMSNorm (swish gate) -------
__global__ void combine_kernel(const float* __restrict__ o_c, const float* __restrict__ qg,
                               const float* __restrict__ norm_w,
                               const int* __restrict__ posg, const float* __restrict__ w01,
                               unsigned short* __restrict__ ocg)
{
    int t = blockIdx.x, h = blockIdx.y;
    int p0 = posg[2 * t], p1 = posg[2 * t + 1];
    float w0 = w01[2 * t], w1 = w01[2 * t + 1];
    int v0 = threadIdx.x, v1 = threadIdx.x + 256;
    size_t r0 = (size_t)p0 * VD + h * DVv, r1 = (size_t)p1 * VD + h * DVv;
    float a  = w0 * o_c[r0 + v0] + w1 * o_c[r1 + v0];
    float b2 = w0 * o_c[r0 + v1] + w1 * o_c[r1 + v1];
    float val = a * a + b2 * b2;
#pragma unroll
    for (int off = 1; off < 64; off <<= 1) val += __shfl_xor(val, off, 64);
    __shared__ float red[4];
    if ((threadIdx.x & 63) == 0) red[threadIdx.x >> 6] = val;
    __syncthreads();
    float total = red[0] + red[1] + red[2] + red[3];
    float rms = rsqrtf(total / 512.f + 1e-5f);
    size_t og = (size_t)t * VD + h * DVv;
    size_t gq = (size_t)t * QGW + KD + h * DVv;
    float g0 = qg[gq + v0], g1 = qg[gq + v1];
    ocg[og + v0] = f2bf(a  * rms * norm_w[v0] * g0 / (1.f + expf(-g0)));
    ocg[og + v1] = f2bf(b2 * rms * norm_w[v1] * g1 / (1.f + expf(-g1)));
}

// ------------------------------------------------------------------ host ----
extern "C" void kernel_launch(void* const* d_in, const int* in_sizes, int n_in,
                              void* d_out, int out_size, void* d_ws, size_t ws_size,
                              hipStream_t stream)
{
    const float* hidden   = (const float*)d_in[0];
    const float* q_w      = (const float*)d_in[1];
    const float* gate_w   = (const float*)d_in[2];
    const float* k_w      = (const float*)d_in[3];
    const float* v_w      = (const float*)d_in[4];
    const float* b_w      = (const float*)d_in[5];
    const float* a_w      = (const float*)d_in[6];
    const float* A_log    = (const float*)d_in[7];
    const float* dt_bias  = (const float*)d_in[8];
    const float* q_conv_w = (const float*)d_in[9];
    const float* k_conv_w = (const float*)d_in[10];
    const float* v_conv_w = (const float*)d_in[11];
    const float* g_w      = (const float*)d_in[12];
    const float* norm_w   = (const float*)d_in[13];
    const float* o_w      = (const float*)d_in[14];
    float* outp = (float*)d_out;

    float* f = (float*)d_ws;
    size_t off = 0;
    auto alloc = [&](size_t n) { float* p = f + off; off += (n + 3) & ~(size_t)3; return p; };
    float* qg     = alloc((size_t)1024 * QGW);    // [t][0:1536]=qh, [1536:4608]=gg
    float* kvraw  = alloc((size_t)2048 * QGW);    // [slot][0:1536]=kraw, [1536:4608]=vraw
    float* qn     = alloc((size_t)2048 * 1536);
    float* kn     = alloc((size_t)2048 * 1536);
    float* vconv  = alloc((size_t)2048 * 3072);
    float* o_c    = alloc((size_t)2048 * 3072);
    float* beta_c = alloc(2048 * 6);
    float* g_c    = alloc(2048 * 6);
    float* qk_c   = alloc(2048 * 6);
    float* w01f   = alloc(2048);

    unsigned short* u = (unsigned short*)(f + off);
    size_t uoff = 0;
    auto ualloc = [&](size_t n) { unsigned short* p = u + uoff; uoff += (n + 7) & ~(size_t)7; return p; };
    unsigned short* hidden_bf = ualloc((size_t)1024 * 2048);
    unsigned short* xe_c      = ualloc((size_t)2048 * 2048);
    unsigned short* ocg       = ualloc((size_t)1024 * 3072);
    unsigned short* qg_wT     = ualloc((size_t)QGW * 2048);       // q rows 0-1535, g rows 1536-4607
    unsigned short* kv_wT     = ualloc((size_t)8 * QGW * 2048);   // per e: k rows 0-1535, v rows 1536-4607
    unsigned short* o_wT      = ualloc((size_t)3072 * 2048);

    int* ib      = (int*)(u + uoff);
    int* sel01   = ib;
    int* list_c  = ib + 2048;
    int* posg    = ib + 4096;
    int* cnt     = ib + 6144;
    int* basearr = ib + 6152;

    const size_t EST = (size_t)2048 * QGW;       // expert stride in fused kv_wT

    router_kernel<<<1024, 64, 0, stream>>>(hidden, gate_w, sel01, w01f);
    dispatch_kernel<<<1, 1024, 0, stream>>>(sel01, list_c, posg, cnt, basearr);

    cast_bf16_kernel<<<2048, 256, 0, stream>>>(hidden, hidden_bf);
    gather_cast_kernel<<<2048, 256, 0, stream>>>(hidden, list_c, xe_c);
    transpose_cast_kernel<<<dim3(64, 48, 1), 256, 0, stream>>>(q_w, qg_wT, 2048, 1536, 0);
    transpose_cast_kernel<<<dim3(64, 96, 1), 256, 0, stream>>>(g_w, qg_wT + (size_t)1536 * 2048, 2048, 3072, 0);
    transpose_cast_kernel<<<dim3(64, 48, 8), 256, 0, stream>>>(k_w, kv_wT, 2048, 1536, EST);
    transpose_cast_kernel<<<dim3(64, 96, 8), 256, 0, stream>>>(v_w, kv_wT + (size_t)1536 * 2048, 2048, 3072, EST);
    transpose_cast_kernel<<<dim3(96, 64, 1), 256, 0, stream>>>(o_w, o_wT, 3072, 2048, 0);

    gemm_bf16<false><<<dim3(8, 36), 256, 0, stream>>>(hidden_bf, qg_wT, qg, nullptr, nullptr, 1024, 2048, QGW);
    gemm_bf16<true ><<<dim3(8, 36, 8), 256, 0, stream>>>(xe_c, kv_wT, kvraw, cnt, basearr, 0, 2048, QGW);

    ba_kernel<<<dim3(1024, 8), 64, 0, stream>>>(hidden, b_w, a_w, A_log, dt_bias,
                                                list_c, cnt, basearr, beta_c, g_c);

    conv_norm_kernel<true ><<<dim3(1024, 8, 6), 256, 0, stream>>>(qg,    QGW, q_conv_w, list_c, cnt, basearr, qn, 0.0625f);
    conv_norm_kernel<false><<<dim3(1024, 8, 6), 256, 0, stream>>>(kvraw, QGW, k_conv_w, list_c, cnt, basearr, kn, 1.0f);
    conv_v_kernel<<<dim3(1024, 8, 12), 256, 0, stream>>>(kvraw, v_conv_w, cnt, basearr, vconv);

    qk_kernel<<<dim3(2048, 6), 64, 0, stream>>>(qn, kn, qk_c);

    recurrence_kernel<<<dim3(16, 6, 8), 256, 0, stream>>>(qn, kn, vconv, beta_c, g_c, qk_c,
                                                          cnt, basearr, o_c);

    combine_kernel<<<dim3(1024, 6), 256, 0, stream>>>(o_c, qg, norm_w, posg, w01f, ocg);
    gemm_bf16<false><<<dim3(8, 16), 256, 0, stream>>>(ocg, o_wT, outp, nullptr, nullptr, 1024, 3072, 2048);
}

// Round 9
// 1077.477 us; speedup vs baseline: 1.2502x; 1.0988x over previous
//
#include <hip/hip_runtime.h>
#include <math.h>

#define Dm    2048
#define Hh    6
#define DKk   256
#define DVv   512
#define KD    1536
#define VD    3072
#define QGW   4608
#define CH    4

typedef __attribute__((ext_vector_type(8))) __bf16 bf16x8;
typedef __attribute__((ext_vector_type(4))) float floatx4;

__device__ __forceinline__ unsigned short f2bf(float f) {
    unsigned int u = __float_as_uint(f);
    u = (u + 0x7fffu + ((u >> 16) & 1u)) >> 16;
    return (unsigned short)u;
}

__device__ __forceinline__ void gl_lds16(const void* g, void* l) {
    __builtin_amdgcn_global_load_lds((const __attribute__((address_space(1))) void*)g,
                                     (__attribute__((address_space(3))) void*)l, 16, 0, 0);
}

// ---------------------------------------------------------------- router ----
__global__ void router_kernel(const float* __restrict__ hidden,
                              const float* __restrict__ gate_w,
                              int* __restrict__ sel01, float* __restrict__ w01)
{
    int t = blockIdx.x;
    int lane = threadIdx.x;                      // 64 threads
    const float* hr = hidden + (size_t)t * Dm;
    float h[32];
#pragma unroll
    for (int i = 0; i < 32; ++i) h[i] = hr[lane + 64 * i];
    float logit[8];
#pragma unroll
    for (int e = 0; e < 8; ++e) {
        float acc = 0.f;
#pragma unroll
        for (int i = 0; i < 32; ++i) acc += h[i] * gate_w[(size_t)(lane + 64 * i) * 8 + e];
#pragma unroll
        for (int off = 1; off < 64; off <<= 1) acc += __shfl_xor(acc, off, 64);
        logit[e] = acc;
    }
    if (lane == 0) {
        int i0 = 0;
#pragma unroll
        for (int e = 1; e < 8; ++e) if (logit[e] > logit[i0]) i0 = e;
        int i1 = (i0 == 0) ? 1 : 0;
#pragma unroll
        for (int e = 0; e < 8; ++e) if (e != i0 && logit[e] > logit[i1]) i1 = e;
        float w0 = 1.f / (1.f + expf(logit[i1] - logit[i0]));
        sel01[2 * t] = i0; sel01[2 * t + 1] = i1;
        w01[2 * t] = w0;   w01[2 * t + 1] = 1.f - w0;
    }
}

// -------------------------------------------------------------- dispatch ----
__global__ void dispatch_kernel(const int* __restrict__ sel01,
                                int* __restrict__ list_c, int* __restrict__ posg,
                                int* __restrict__ cnt, int* __restrict__ basearr)
{
    __shared__ int wbase[16];
    __shared__ int sbase;
    int t = threadIdx.x;
    int lane = t & 63, w = t >> 6;
    int s0 = sel01[2 * t], s1 = sel01[2 * t + 1];
    if (t == 0) sbase = 0;
    __syncthreads();
    for (int e = 0; e < 8; ++e) {
        int flag  = (s0 == e || s1 == e) ? 1 : 0;
        int kslot = (s0 == e) ? 0 : 1;
        unsigned long long m = __ballot(flag);
        int lpre = __popcll(m & ((1ull << lane) - 1ull));
        if (lane == 0) wbase[w] = __popcll(m);
        __syncthreads();
        if (t == 0) {
            int run = sbase;
            basearr[e] = run;
            for (int i = 0; i < 16; ++i) { int tv = wbase[i]; wbase[i] = run; run += tv; }
            cnt[e] = run - sbase;
            sbase = run;
        }
        __syncthreads();
        if (flag) {
            int pos = wbase[w] + lpre;
            list_c[pos] = t;
            posg[2 * t + kslot] = pos;
        }
        __syncthreads();
    }
}

// ------------------------------------------------------------ bf16 casts ----
__global__ void cast_bf16_kernel(const float* __restrict__ x, unsigned short* __restrict__ y)
{
    int i = (blockIdx.x * 256 + threadIdx.x) * 4;
    float4 a = *(const float4*)(x + i);
    ushort4 o;
    o.x = f2bf(a.x); o.y = f2bf(a.y); o.z = f2bf(a.z); o.w = f2bf(a.w);
    *(ushort4*)(y + i) = o;
}

__global__ void gather_cast_kernel(const float* __restrict__ hidden, const int* __restrict__ list,
                                   unsigned short* __restrict__ xe)
{
    int slot = blockIdx.x;
    int tok = list[slot];
    const float* src = hidden + (size_t)tok * Dm;
    unsigned short* dst = xe + (size_t)slot * Dm;
    int c = threadIdx.x * 8;
    float4 a = *(const float4*)(src + c);
    float4 b = *(const float4*)(src + c + 4);
    ushort4 o1, o2;
    o1.x = f2bf(a.x); o1.y = f2bf(a.y); o1.z = f2bf(a.z); o1.w = f2bf(a.w);
    o2.x = f2bf(b.x); o2.y = f2bf(b.y); o2.z = f2bf(b.z); o2.w = f2bf(b.w);
    *(ushort4*)(dst + c) = o1;
    *(ushort4*)(dst + c + 4) = o2;
}

// fp32 [b][K][N] -> bf16 [b][N][K] at expert stride estride (fused buffers).
// R6: write phase vectorized (ushort4 per thread).
__global__ void transpose_cast_kernel(const float* __restrict__ in, unsigned short* __restrict__ out,
                                      int K, int N, size_t estride)
{
    __shared__ float tile[32][33];
    int b = blockIdx.z;
    int k0 = blockIdx.x * 32, n0 = blockIdx.y * 32;
    const float* ip = in + (size_t)b * K * N;
    unsigned short* op = out + (size_t)b * estride;
    int tx = threadIdx.x & 31, ty = threadIdx.x >> 5;   // 32 x 8 load phase
#pragma unroll
    for (int i = 0; i < 4; ++i)
        tile[ty + i * 8][tx] = ip[(size_t)(k0 + ty + i * 8) * N + n0 + tx];
    __syncthreads();
    int kq = threadIdx.x & 7, n = threadIdx.x >> 3;     // 8 x 32 store phase
    ushort4 o;
    o.x = f2bf(tile[kq * 4 + 0][n]);
    o.y = f2bf(tile[kq * 4 + 1][n]);
    o.z = f2bf(tile[kq * 4 + 2][n]);
    o.w = f2bf(tile[kq * 4 + 3][n]);
    *(ushort4*)(op + (size_t)(n0 + n) * K + k0 + kq * 4) = o;
}

// ----------------------------------------------------------- bf16 GEMM ------
// C[M][N] = A[M][K] * Bt[N][K]^T, 128x128 tile, BK=32, mfma 16x16x32 bf16.
// R8: XOR-swizzled LDS (pre-swizzled global source slot, rule #21) killed the
// 8-way ds_read conflict; expert path 2-buf landed kv at ~248us (from 297) --
// still fetch-bound at only 750 GB/s. R9 diagnosis: grid (x=m:8,...) puts the
// 2-of-8 active m-blocks in pairs every 8 linear IDs -> active blocks cluster
// on a fraction of CUs (R7 occupancy 5.6%); depth-2 covers only ~300cyc of
// ~900cyc HBM latency. R9 fixes (EXPERT only):
//  (a) grid reorder (x=n:36, y=m:8, z=e): actives form runs of 72 consecutive
//      IDs -> uniform CU spread.
//  (b) NBUF=3 (48 KiB, 3 blocks/CU cap >= ~2.25 supplied): load-to-use = 2
//      iters ~ 500-600 cyc, covers HBM. vmcnt(8/4/0) counted ladder.
// Non-expert grids (~1 block/CU, no TLP) keep 4-buf depth-3, x=m, y=n.
template<bool EXPERT>
__global__ __launch_bounds__(256)
void gemm_bf16(const unsigned short* __restrict__ A,
               const unsigned short* __restrict__ Bt,
               float* __restrict__ C,
               const int* __restrict__ cnt, const int* __restrict__ basearr,
               int M, int K, int N)
{
    constexpr int NBUF = EXPERT ? 3 : 4;
    int e = EXPERT ? blockIdx.z : 0;
    int Mloc = M, base = 0;
    int mblk = EXPERT ? blockIdx.y : blockIdx.x;
    int nblk = EXPERT ? blockIdx.x : blockIdx.y;
    if (EXPERT) {
        Mloc = cnt[e]; base = basearr[e];
        if ((int)(mblk * 128) >= Mloc) return;
    }
    int m0 = mblk * 128, n0 = nblk * 128;
    const unsigned short* Ab = A + (size_t)base * K;
    const unsigned short* Bb = Bt + (size_t)e * (size_t)K * N;
    __shared__ unsigned short As[NBUF][128 * 32];
    __shared__ unsigned short Bs[NBUF][128 * 32];
    int tid = threadIdx.x;
    int lane = tid & 63, wave = tid >> 6;
    const unsigned short* ga[2];
    const unsigned short* gb[2];
    int lo[2];
#pragma unroll
    for (int j = 0; j < 2; ++j) {
        int flat = j * 256 + tid;
        int row = flat >> 2, sub = flat & 3;
        int subs = sub ^ ((row >> 1) & 3);       // pre-swizzled source slot
        int ar = m0 + row; if (ar > Mloc - 1) ar = Mloc - 1;
        ga[j] = Ab + (size_t)ar * K + subs * 8;
        gb[j] = Bb + (size_t)(n0 + row) * K + subs * 8;
        lo[j] = flat * 8;                        // linear LDS dest
    }
    floatx4 acc[4][4];
#pragma unroll
    for (int i = 0; i < 4; ++i)
#pragma unroll
        for (int j = 0; j < 4; ++j) acc[i][j] = (floatx4){0.f, 0.f, 0.f, 0.f};

    int wm = (wave >> 1) * 64, wn = (wave & 1) * 64;
    int fr = lane & 15, q = lane >> 4;
    int qs = q ^ ((fr >> 1) & 3);                // read slot after swizzle

    int nk = K >> 5;
    auto stage = [&](int buf, int t) {
        int k0 = t << 5;
        gl_lds16(ga[0] + k0, As[buf] + lo[0]);
        gl_lds16(gb[0] + k0, Bs[buf] + lo[0]);
        gl_lds16(ga[1] + k0, As[buf] + lo[1]);
        gl_lds16(gb[1] + k0, Bs[buf] + lo[1]);
    };
#pragma unroll
    for (int b = 0; b < NBUF - 1; ++b) stage(b, b);
    int cur = 0;
    for (int t = 0; t < nk; ++t) {
        int nxt = cur + (NBUF - 1); if (nxt >= NBUF) nxt -= NBUF;
        if (t + NBUF - 1 < nk) stage(nxt, t + NBUF - 1);
        int ahead = nk - 1 - t;
        if constexpr (EXPERT) {
            if (ahead >= 2)      asm volatile("s_waitcnt vmcnt(8)\n\ts_barrier" ::: "memory");
            else if (ahead == 1) asm volatile("s_waitcnt vmcnt(4)\n\ts_barrier" ::: "memory");
            else                 asm volatile("s_waitcnt vmcnt(0)\n\ts_barrier" ::: "memory");
        } else {
            if (ahead >= 3)      asm volatile("s_waitcnt vmcnt(12)\n\ts_barrier" ::: "memory");
            else if (ahead == 2) asm volatile("s_waitcnt vmcnt(8)\n\ts_barrier" ::: "memory");
            else if (ahead == 1) asm volatile("s_waitcnt vmcnt(4)\n\ts_barrier" ::: "memory");
            else                 asm volatile("s_waitcnt vmcnt(0)\n\ts_barrier" ::: "memory");
        }
        bf16x8 af[4], bfr[4];
        const unsigned short* Ac = As[cur];
        const unsigned short* Bc = Bs[cur];
#pragma unroll
        for (int f = 0; f < 4; ++f) {
            af[f]  = *(const bf16x8*)(Ac + (size_t)(wm + f * 16 + fr) * 32 + qs * 8);
            bfr[f] = *(const bf16x8*)(Bc + (size_t)(wn + f * 16 + fr) * 32 + qs * 8);
        }
#pragma unroll
        for (int fm = 0; fm < 4; ++fm)
#pragma unroll
            for (int fn = 0; fn < 4; ++fn)
                acc[fm][fn] = __builtin_amdgcn_mfma_f32_16x16x32_bf16(af[fm], bfr[fn], acc[fm][fn], 0, 0, 0);
        asm volatile("s_waitcnt lgkmcnt(0)\n\ts_barrier" ::: "memory");
        cur = cur + 1 == NBUF ? 0 : cur + 1;
    }
    int rb = q * 4;
#pragma unroll
    for (int fm = 0; fm < 4; ++fm) {
#pragma unroll
        for (int r = 0; r < 4; ++r) {
            int m = m0 + wm + fm * 16 + rb + r;
            if (m < Mloc) {
                float* cp = C + (size_t)(base + m) * N + n0 + wn + fr;
#pragma unroll
                for (int fn = 0; fn < 4; ++fn)
                    cp[fn * 16] = acc[fm][fn][r];
            }
        }
    }
}

// ------------------------------------------- beta / g small projections ----
__global__ void ba_kernel(const float* __restrict__ hidden,
                          const float* __restrict__ b_w, const float* __restrict__ a_w,
                          const float* __restrict__ A_log, const float* __restrict__ dt_bias,
                          const int* __restrict__ list, const int* __restrict__ cnt,
                          const int* __restrict__ basearr,
                          float* __restrict__ beta_c, float* __restrict__ g_c)
{
    int j = blockIdx.x, e = blockIdx.y;
    if (j >= cnt[e]) return;
    int gpos = basearr[e] + j;
    int tok = list[gpos];
    int lane = threadIdx.x;                      // 64
    const float* hr = hidden + (size_t)tok * Dm;
    float h[32];
#pragma unroll
    for (int i = 0; i < 32; ++i) h[i] = hr[lane + 64 * i];
    for (int c = 0; c < 12; ++c) {
        int col = c % 6;
        const float* W = ((c < 6) ? b_w : a_w) + (size_t)e * Dm * 6;
        float acc = 0.f;
#pragma unroll
        for (int i = 0; i < 32; ++i) acc += h[i] * W[(size_t)(lane + 64 * i) * 6 + col];
#pragma unroll
        for (int off = 1; off < 64; off <<= 1) acc += __shfl_xor(acc, off, 64);
        if (lane == 0) {
            if (c < 6) {
                beta_c[gpos * 6 + col] = 1.f / (1.f + expf(-acc));
            } else {
                float x = acc + dt_bias[col];
                float sp = (x > 20.f) ? x : log1pf(expf(x));
                g_c[gpos * 6 + col] = -expf(A_log[col]) * sp;
            }
        }
    }
}

// -------------------------------------- causal conv4 + silu (+ l2 norm) ----
template<bool GATHER>
__global__ void conv_norm_kernel(const float* __restrict__ X, int xstride,
                                 const float* __restrict__ convw,
                                 const int* __restrict__ list, const int* __restrict__ cnt,
                                 const int* __restrict__ basearr,
                                 float* __restrict__ outb, float scale)
{
    int j = blockIdx.x, e = blockIdx.y, h = blockIdx.z;
    if (j >= cnt[e]) return;
    int base = basearr[e];
    int gpos = base + j;
    int c = h * DKk + threadIdx.x;               // 256 threads
    float acc = 0.f;
#pragma unroll
    for (int tau = 0; tau < 4; ++tau) {
        int jj = j - 3 + tau;
        if (jj >= 0) {
            const float* row = GATHER ? (X + (size_t)list[base + jj] * xstride)
                                      : (X + (size_t)(base + jj) * xstride);
            acc += row[c] * convw[c * 4 + tau];
        }
    }
    float y = acc / (1.f + expf(-acc));          // silu
    float v = y * y;
#pragma unroll
    for (int off = 1; off < 64; off <<= 1) v += __shfl_xor(v, off, 64);
    __shared__ float red[4];
    if ((threadIdx.x & 63) == 0) red[threadIdx.x >> 6] = v;
    __syncthreads();
    float total = red[0] + red[1] + red[2] + red[3];
    outb[(size_t)gpos * KD + c] = y * rsqrtf(total + 1e-6f) * scale;
}

// v-conv reads fused kv rows, cols KD..KD+VD-1.
__global__ void conv_v_kernel(const float* __restrict__ X,
                              const float* __restrict__ convw,
                              const int* __restrict__ cnt, const int* __restrict__ basearr,
                              float* __restrict__ outb)
{
    int j = blockIdx.x, e = blockIdx.y;
    if (j >= cnt[e]) return;
    int base = basearr[e];
    int gpos = base + j;
    int c = blockIdx.z * 256 + threadIdx.x;      // 12 * 256 = 3072
    float acc = 0.f;
#pragma unroll
    for (int tau = 0; tau < 4; ++tau) {
        int jj = j - 3 + tau;
        if (jj >= 0) acc += X[(size_t)(base + jj) * QGW + KD + c] * convw[c * 4 + tau];
    }
    outb[(size_t)gpos * VD + c] = acc / (1.f + expf(-acc));
}

// ------------------------------------------------ qk = q . k precompute ----
__global__ void qk_kernel(const float* __restrict__ qn, const float* __restrict__ kn,
                          float* __restrict__ qk_c)
{
    int gpos = blockIdx.x, h = blockIdx.y;
    int lane = threadIdx.x;                      // 64
    const float4* qp = (const float4*)(qn + (size_t)gpos * KD + h * DKk);
    const float4* kp = (const float4*)(kn + (size_t)gpos * KD + h * DKk);
    float4 a = qp[lane], b = kp[lane];
    float acc = a.x * b.x + a.y * b.y + a.z * b.z + a.w * b.w;
#pragma unroll
    for (int off = 1; off < 64; off <<= 1) acc += __shfl_xor(acc, off, 64);
    if (lane == 0) qk_c[(size_t)gpos * Hh + h] = acc;
}

// --------------------------------------------- gated delta rule (serial) ----
// EXACT R4 configuration (measured 266-268 us): grid (16,H,E)=768 blocks =
// 3 blocks/CU single pass; thread = (kpart 0..7, vcol 0..31). k/q staged in
// LDS via gl_lds16 (double-buffered CH=4 chunks, counted vmcnt(2)); scalars
// chunk-prefetched; qk hoisted. (R5 finer split regressed: 2 dispatch passes.)
__global__ __launch_bounds__(256, 3)
void recurrence_kernel(const float* __restrict__ qn, const float* __restrict__ kn,
                       const float* __restrict__ vc,
                       const float* __restrict__ beta_c, const float* __restrict__ g_c,
                       const float* __restrict__ qk_c,
                       const int* __restrict__ cnt, const int* __restrict__ basearr,
                       float* __restrict__ o_c)
{
    int vb = blockIdx.x, h = blockIdx.y, e = blockIdx.z;
    int n = cnt[e], base = basearr[e];
    if (n <= 0) return;
    int tid = threadIdx.x;
    int kpart = tid & 7, vcol = tid >> 3;
    int v = vb * 32 + vcol;
    int wv = tid >> 6, lane = tid & 63;

    __shared__ float lk[2][CH][256];             // 8 KB
    __shared__ float lq[2][CH][256];             // 8 KB

    const float* kb = kn + (size_t)base * KD + h * DKk;
    const float* qb = qn + (size_t)base * KD + h * DKk;
    const float* vp = vc + (size_t)base * VD + h * DVv + v;
    const float* gp = g_c    + (size_t)base * Hh + h;
    const float* bp = beta_c + (size_t)base * Hh + h;
    const float* xp = qk_c   + (size_t)base * Hh + h;
    float* op = o_c + (size_t)base * VD + h * DVv + v;

    float4 s[8];
#pragma unroll
    for (int i = 0; i < 8; ++i) s[i] = make_float4(0.f, 0.f, 0.f, 0.f);

    int nch = (n + CH - 1) / CH;

    auto stageKQ = [&](int buf, int c) {
        int jj = c * CH + wv; if (jj > n - 1) jj = n - 1;
        gl_lds16(kb + (size_t)jj * KD + lane * 4, &lk[buf][wv][lane * 4]);
        gl_lds16(qb + (size_t)jj * KD + lane * 4, &lq[buf][wv][lane * 4]);
    };

    float vA[CH], gA[CH], bA[CH], xA[CH];
    float vB[CH], gB[CH], bB[CH], xB[CH];

    auto loadScal = [&](float (&V)[CH], float (&G)[CH], float (&B)[CH], float (&X)[CH], int c) {
#pragma unroll
        for (int u = 0; u < CH; ++u) {
            int jj = c * CH + u; if (jj > n - 1) jj = n - 1;
            V[u] = vp[(size_t)jj * VD];
            G[u] = gp[(size_t)jj * Hh];
            B[u] = bp[(size_t)jj * Hh];
            X[u] = xp[(size_t)jj * Hh];
        }
    };

    auto computeChunk = [&](const float (&Lk)[CH][256], const float (&Lq)[CH][256],
                            const float (&V)[CH], const float (&G)[CH],
                            const float (&B)[CH], const float (&X)[CH], int c) {
#pragma unroll
        for (int u = 0; u < CH; ++u) {
            const float* Lku = &Lk[u][kpart * 4];
            const float* Lqu = &Lq[u][kpart * 4];
            float4 pa0 = make_float4(0.f,0.f,0.f,0.f), pa1 = make_float4(0.f,0.f,0.f,0.f);
            float4 ra0 = make_float4(0.f,0.f,0.f,0.f), ra1 = make_float4(0.f,0.f,0.f,0.f);
            float4 kk[8];
#pragma unroll
            for (int i = 0; i < 8; ++i) {
                kk[i] = *(const float4*)(Lku + i * 32);
                float4 qq = *(const float4*)(Lqu + i * 32);
                float4& pa = (i & 1) ? pa1 : pa0;
                float4& ra = (i & 1) ? ra1 : ra0;
                pa.x = fmaf(kk[i].x, s[i].x, pa.x); pa.y = fmaf(kk[i].y, s[i].y, pa.y);
                pa.z = fmaf(kk[i].z, s[i].z, pa.z); pa.w = fmaf(kk[i].w, s[i].w, pa.w);
                ra.x = fmaf(qq.x, s[i].x, ra.x); ra.y = fmaf(qq.y, s[i].y, ra.y);
                ra.z = fmaf(qq.z, s[i].z, ra.z); ra.w = fmaf(qq.w, s[i].w, ra.w);
            }
            float p = ((pa0.x + pa1.x) + (pa0.y + pa1.y)) + ((pa0.z + pa1.z) + (pa0.w + pa1.w));
            float r = ((ra0.x + ra1.x) + (ra0.y + ra1.y)) + ((ra0.z + ra1.z) + (ra0.w + ra1.w));
#pragma unroll
            for (int m = 1; m < 8; m <<= 1) {
                p += __shfl_xor(p, m, 64);
                r += __shfl_xor(r, m, 64);
            }
            float eg = __expf(G[u]);
            float delta = (V[u] - p * eg) * B[u];
            float out = fmaf(X[u], delta, eg * r);
#pragma unroll
            for (int i = 0; i < 8; ++i) {
                s[i].x = fmaf(eg, s[i].x, kk[i].x * delta);
                s[i].y = fmaf(eg, s[i].y, kk[i].y * delta);
                s[i].z = fmaf(eg, s[i].z, kk[i].z * delta);
                s[i].w = fmaf(eg, s[i].w, kk[i].w * delta);
            }
            int j = c * CH + u;
            if (kpart == 0 && j < n) op[(size_t)j * VD] = out;
        }
    };

    stageKQ(0, 0);
    loadScal(vA, gA, bA, xA, 0);
    stageKQ(1, 1);
    asm volatile("s_waitcnt vmcnt(2)\n\ts_barrier" ::: "memory");

    for (int c = 0; c < nch; c += 2) {
        loadScal(vB, gB, bB, xB, c + 1);
        computeChunk(lk[0], lq[0], vA, gA, bA, xA, c);
        __syncthreads();
        stageKQ(0, c + 2);
        asm volatile("s_waitcnt vmcnt(2)\n\ts_barrier" ::: "memory");
        if (c + 1 >= nch) break;
        loadScal(vA, gA, bA, xA, c + 2);
        computeChunk(lk[1], lq[1], vB, gB, bB, xB, c + 1);
        __syncthreads();
        stageKQ(1, c + 3);
        asm volatile("s_waitcnt vmcnt(2)\n\ts_barrier" ::: "memory");
    }
    asm volatile("s_waitcnt vmcnt(0)" ::: "memory");
}

// ------------------------------- combine + gated RMSNorm (swish gate) -------
__global__ void combine_kernel(const float* __restrict__ o_c, const float* __restrict__ qg,
                               const float* __restrict__ norm_w,
                               const int* __restrict__ posg, const float* __restrict__ w01,
                               unsigned short* __restrict__ ocg)
{
    int t = blockIdx.x, h = blockIdx.y;
    int p0 = posg[2 * t], p1 = posg[2 * t + 1];
    float w0 = w01[2 * t], w1 = w01[2 * t + 1];
    int v0 = threadIdx.x, v1 = threadIdx.x + 256;
    size_t r0 = (size_t)p0 * VD + h * DVv, r1 = (size_t)p1 * VD + h * DVv;
    float a  = w0 * o_c[r0 + v0] + w1 * o_c[r1 + v0];
    float b2 = w0 * o_c[r0 + v1] + w1 * o_c[r1 + v1];
    float val = a * a + b2 * b2;
#pragma unroll
    for (int off = 1; off < 64; off <<= 1) val += __shfl_xor(val, off, 64);
    __shared__ float red[4];
    if ((threadIdx.x & 63) == 0) red[threadIdx.x >> 6] = val;
    __syncthreads();
    float total = red[0] + red[1] + red[2] + red[3];
    float rms = rsqrtf(total / 512.f + 1e-5f);
    size_t og = (size_t)t * VD + h * DVv;
    size_t gq = (size_t)t * QGW + KD + h * DVv;
    float g0 = qg[gq + v0], g1 = qg[gq + v1];
    ocg[og + v0] = f2bf(a  * rms * norm_w[v0] * g0 / (1.f + expf(-g0)));
    ocg[og + v1] = f2bf(b2 * rms * norm_w[v1] * g1 / (1.f + expf(-g1)));
}

// ------------------------------------------------------------------ host ----
extern "C" void kernel_launch(void* const* d_in, const int* in_sizes, int n_in,
                              void* d_out, int out_size, void* d_ws, size_t ws_size,
                              hipStream_t stream)
{
    const float* hidden   = (const float*)d_in[0];
    const float* q_w      = (const float*)d_in[1];
    const float* gate_w   = (const float*)d_in[2];
    const float* k_w      = (const float*)d_in[3];
    const float* v_w      = (const float*)d_in[4];
    const float* b_w      = (const float*)d_in[5];
    const float* a_w      = (const float*)d_in[6];
    const float* A_log    = (const float*)d_in[7];
    const float* dt_bias  = (const float*)d_in[8];
    const float* q_conv_w = (const float*)d_in[9];
    const float* k_conv_w = (const float*)d_in[10];
    const float* v_conv_w = (const float*)d_in[11];
    const float* g_w      = (const float*)d_in[12];
    const float* norm_w   = (const float*)d_in[13];
    const float* o_w      = (const float*)d_in[14];
    float* outp = (float*)d_out;

    float* f = (float*)d_ws;
    size_t off = 0;
    auto alloc = [&](size_t n) { float* p = f + off; off += (n + 3) & ~(size_t)3; return p; };
    float* qg     = alloc((size_t)1024 * QGW);    // [t][0:1536]=qh, [1536:4608]=gg
    float* kvraw  = alloc((size_t)2048 * QGW);    // [slot][0:1536]=kraw, [1536:4608]=vraw
    float* qn     = alloc((size_t)2048 * 1536);
    float* kn     = alloc((size_t)2048 * 1536);
    float* vconv  = alloc((size_t)2048 * 3072);
    float* o_c    = alloc((size_t)2048 * 3072);
    float* beta_c = alloc(2048 * 6);
    float* g_c    = alloc(2048 * 6);
    float* qk_c   = alloc(2048 * 6);
    float* w01f   = alloc(2048);

    unsigned short* u = (unsigned short*)(f + off);
    size_t uoff = 0;
    auto ualloc = [&](size_t n) { unsigned short* p = u + uoff; uoff += (n + 7) & ~(size_t)7; return p; };
    unsigned short* hidden_bf = ualloc((size_t)1024 * 2048);
    unsigned short* xe_c      = ualloc((size_t)2048 * 2048);
    unsigned short* ocg       = ualloc((size_t)1024 * 3072);
    unsigned short* qg_wT     = ualloc((size_t)QGW * 2048);       // q rows 0-1535, g rows 1536-4607
    unsigned short* kv_wT     = ualloc((size_t)8 * QGW * 2048);   // per e: k rows 0-1535, v rows 1536-4607
    unsigned short* o_wT      = ualloc((size_t)3072 * 2048);

    int* ib      = (int*)(u + uoff);
    int* sel01   = ib;
    int* list_c  = ib + 2048;
    int* posg    = ib + 4096;
    int* cnt     = ib + 6144;
    int* basearr = ib + 6152;

    const size_t EST = (size_t)2048 * QGW;       // expert stride in fused kv_wT

    router_kernel<<<1024, 64, 0, stream>>>(hidden, gate_w, sel01, w01f);
    dispatch_kernel<<<1, 1024, 0, stream>>>(sel01, list_c, posg, cnt, basearr);

    cast_bf16_kernel<<<2048, 256, 0, stream>>>(hidden, hidden_bf);
    gather_cast_kernel<<<2048, 256, 0, stream>>>(hidden, list_c, xe_c);
    transpose_cast_kernel<<<dim3(64, 48, 1), 256, 0, stream>>>(q_w, qg_wT, 2048, 1536, 0);
    transpose_cast_kernel<<<dim3(64, 96, 1), 256, 0, stream>>>(g_w, qg_wT + (size_t)1536 * 2048, 2048, 3072, 0);
    transpose_cast_kernel<<<dim3(64, 48, 8), 256, 0, stream>>>(k_w, kv_wT, 2048, 1536, EST);
    transpose_cast_kernel<<<dim3(64, 96, 8), 256, 0, stream>>>(v_w, kv_wT + (size_t)1536 * 2048, 2048, 3072, EST);
    transpose_cast_kernel<<<dim3(96, 64, 1), 256, 0, stream>>>(o_w, o_wT, 3072, 2048, 0);

    gemm_bf16<false><<<dim3(8, 36), 256, 0, stream>>>(hidden_bf, qg_wT, qg, nullptr, nullptr, 1024, 2048, QGW);
    gemm_bf16<true ><<<dim3(36, 8, 8), 256, 0, stream>>>(xe_c, kv_wT, kvraw, cnt, basearr, 0, 2048, QGW);

    ba_kernel<<<dim3(1024, 8), 64, 0, stream>>>(hidden, b_w, a_w, A_log, dt_bias,
                                                list_c, cnt, basearr, beta_c, g_c);

    conv_norm_kernel<true ><<<dim3(1024, 8, 6), 256, 0, stream>>>(qg,    QGW, q_conv_w, list_c, cnt, basearr, qn, 0.0625f);
    conv_norm_kernel<false><<<dim3(1024, 8, 6), 256, 0, stream>>>(kvraw, QGW, k_conv_w, list_c, cnt, basearr, kn, 1.0f);
    conv_v_kernel<<<dim3(1024, 8, 12), 256, 0, stream>>>(kvraw, v_conv_w, cnt, basearr, vconv);

    qk_kernel<<<dim3(2048, 6), 64, 0, stream>>>(qn, kn, qk_c);

    recurrence_kernel<<<dim3(16, 6, 8), 256, 0, stream>>>(qn, kn, vconv, beta_c, g_c, qk_c,
                                                          cnt, basearr, o_c);

    combine_kernel<<<dim3(1024, 6), 256, 0, stream>>>(o_c, qg, norm_w, posg, w01f, ocg);
    gemm_bf16<false><<<dim3(8, 16), 256, 0, stream>>>(ocg, o_wT, outp, nullptr, nullptr, 1024, 3072, 2048);
}

// Round 10
// 1051.662 us; speedup vs baseline: 1.2809x; 1.0245x over previous
//
#include <hip/hip_runtime.h>
#include <math.h>

#define Dm    2048
#define Hh    6
#define DKk   256
#define DVv   512
#define KD    1536
#define VD    3072
#define QGW   4608
#define CH    4

typedef __attribute__((ext_vector_type(8))) __bf16 bf16x8;
typedef __attribute__((ext_vector_type(4))) float floatx4;

__device__ __forceinline__ unsigned short f2bf(float f) {
    unsigned int u = __float_as_uint(f);
    u = (u + 0x7fffu + ((u >> 16) & 1u)) >> 16;
    return (unsigned short)u;
}

__device__ __forceinline__ void gl_lds16(const void* g, void* l) {
    __builtin_amdgcn_global_load_lds((const __attribute__((address_space(1))) void*)g,
                                     (__attribute__((address_space(3))) void*)l, 16, 0, 0);
}

// ---------------------------------------------------------------- router ----
__global__ void router_kernel(const float* __restrict__ hidden,
                              const float* __restrict__ gate_w,
                              int* __restrict__ sel01, float* __restrict__ w01)
{
    int t = blockIdx.x;
    int lane = threadIdx.x;                      // 64 threads
    const float* hr = hidden + (size_t)t * Dm;
    float h[32];
#pragma unroll
    for (int i = 0; i < 32; ++i) h[i] = hr[lane + 64 * i];
    float logit[8];
#pragma unroll
    for (int e = 0; e < 8; ++e) {
        float acc = 0.f;
#pragma unroll
        for (int i = 0; i < 32; ++i) acc += h[i] * gate_w[(size_t)(lane + 64 * i) * 8 + e];
#pragma unroll
        for (int off = 1; off < 64; off <<= 1) acc += __shfl_xor(acc, off, 64);
        logit[e] = acc;
    }
    if (lane == 0) {
        int i0 = 0;
#pragma unroll
        for (int e = 1; e < 8; ++e) if (logit[e] > logit[i0]) i0 = e;
        int i1 = (i0 == 0) ? 1 : 0;
#pragma unroll
        for (int e = 0; e < 8; ++e) if (e != i0 && logit[e] > logit[i1]) i1 = e;
        float w0 = 1.f / (1.f + expf(logit[i1] - logit[i0]));
        sel01[2 * t] = i0; sel01[2 * t + 1] = i1;
        w01[2 * t] = w0;   w01[2 * t + 1] = 1.f - w0;
    }
}

// -------------------------------------------------------------- dispatch ----
__global__ void dispatch_kernel(const int* __restrict__ sel01,
                                int* __restrict__ list_c, int* __restrict__ posg,
                                int* __restrict__ cnt, int* __restrict__ basearr)
{
    __shared__ int wbase[16];
    __shared__ int sbase;
    int t = threadIdx.x;
    int lane = t & 63, w = t >> 6;
    int s0 = sel01[2 * t], s1 = sel01[2 * t + 1];
    if (t == 0) sbase = 0;
    __syncthreads();
    for (int e = 0; e < 8; ++e) {
        int flag  = (s0 == e || s1 == e) ? 1 : 0;
        int kslot = (s0 == e) ? 0 : 1;
        unsigned long long m = __ballot(flag);
        int lpre = __popcll(m & ((1ull << lane) - 1ull));
        if (lane == 0) wbase[w] = __popcll(m);
        __syncthreads();
        if (t == 0) {
            int run = sbase;
            basearr[e] = run;
            for (int i = 0; i < 16; ++i) { int tv = wbase[i]; wbase[i] = run; run += tv; }
            cnt[e] = run - sbase;
            sbase = run;
        }
        __syncthreads();
        if (flag) {
            int pos = wbase[w] + lpre;
            list_c[pos] = t;
            posg[2 * t + kslot] = pos;
        }
        __syncthreads();
    }
}

// ------------------------------------------------------------ bf16 casts ----
__global__ void cast_bf16_kernel(const float* __restrict__ x, unsigned short* __restrict__ y)
{
    int i = (blockIdx.x * 256 + threadIdx.x) * 4;
    float4 a = *(const float4*)(x + i);
    ushort4 o;
    o.x = f2bf(a.x); o.y = f2bf(a.y); o.z = f2bf(a.z); o.w = f2bf(a.w);
    *(ushort4*)(y + i) = o;
}

__global__ void gather_cast_kernel(const float* __restrict__ hidden, const int* __restrict__ list,
                                   unsigned short* __restrict__ xe)
{
    int slot = blockIdx.x;
    int tok = list[slot];
    const float* src = hidden + (size_t)tok * Dm;
    unsigned short* dst = xe + (size_t)slot * Dm;
    int c = threadIdx.x * 8;
    float4 a = *(const float4*)(src + c);
    float4 b = *(const float4*)(src + c + 4);
    ushort4 o1, o2;
    o1.x = f2bf(a.x); o1.y = f2bf(a.y); o1.z = f2bf(a.z); o1.w = f2bf(a.w);
    o2.x = f2bf(b.x); o2.y = f2bf(b.y); o2.z = f2bf(b.z); o2.w = f2bf(b.w);
    *(ushort4*)(dst + c) = o1;
    *(ushort4*)(dst + c + 4) = o2;
}

// fp32 [b][K][N] -> bf16 [b][N][K] at expert stride estride (fused buffers).
// R6: write phase vectorized (ushort4 per thread).
__global__ void transpose_cast_kernel(const float* __restrict__ in, unsigned short* __restrict__ out,
                                      int K, int N, size_t estride)
{
    __shared__ float tile[32][33];
    int b = blockIdx.z;
    int k0 = blockIdx.x * 32, n0 = blockIdx.y * 32;
    const float* ip = in + (size_t)b * K * N;
    unsigned short* op = out + (size_t)b * estride;
    int tx = threadIdx.x & 31, ty = threadIdx.x >> 5;   // 32 x 8 load phase
#pragma unroll
    for (int i = 0; i < 4; ++i)
        tile[ty + i * 8][tx] = ip[(size_t)(k0 + ty + i * 8) * N + n0 + tx];
    __syncthreads();
    int kq = threadIdx.x & 7, n = threadIdx.x >> 3;     // 8 x 32 store phase
    ushort4 o;
    o.x = f2bf(tile[kq * 4 + 0][n]);
    o.y = f2bf(tile[kq * 4 + 1][n]);
    o.z = f2bf(tile[kq * 4 + 2][n]);
    o.w = f2bf(tile[kq * 4 + 3][n]);
    *(ushort4*)(op + (size_t)(n0 + n) * K + k0 + kq * 4) = o;
}

// ----------------------------------------------------------- bf16 GEMM ------
// C[M][N] = A[M][K] * Bt[N][K]^T, 128x128 tile, BK=32, mfma 16x16x32 bf16.
// Verified R9 config (kv ~297->~140us): EXPERT: grid (x=n,y=m,z=e) spreads
// active blocks uniformly; NBUF=3 (48KiB, 3 blocks/CU) covers HBM latency;
// XOR-swizzled LDS via pre-swizzled global source (rule #21). Non-expert
// (~1 block/CU, no TLP): 4-buf depth-3, x=m,y=n. Counted vmcnt ladders.
template<bool EXPERT>
__global__ __launch_bounds__(256)
void gemm_bf16(const unsigned short* __restrict__ A,
               const unsigned short* __restrict__ Bt,
               float* __restrict__ C,
               const int* __restrict__ cnt, const int* __restrict__ basearr,
               int M, int K, int N)
{
    constexpr int NBUF = EXPERT ? 3 : 4;
    int e = EXPERT ? blockIdx.z : 0;
    int Mloc = M, base = 0;
    int mblk = EXPERT ? blockIdx.y : blockIdx.x;
    int nblk = EXPERT ? blockIdx.x : blockIdx.y;
    if (EXPERT) {
        Mloc = cnt[e]; base = basearr[e];
        if ((int)(mblk * 128) >= Mloc) return;
    }
    int m0 = mblk * 128, n0 = nblk * 128;
    const unsigned short* Ab = A + (size_t)base * K;
    const unsigned short* Bb = Bt + (size_t)e * (size_t)K * N;
    __shared__ unsigned short As[NBUF][128 * 32];
    __shared__ unsigned short Bs[NBUF][128 * 32];
    int tid = threadIdx.x;
    int lane = tid & 63, wave = tid >> 6;
    const unsigned short* ga[2];
    const unsigned short* gb[2];
    int lo[2];
#pragma unroll
    for (int j = 0; j < 2; ++j) {
        int flat = j * 256 + tid;
        int row = flat >> 2, sub = flat & 3;
        int subs = sub ^ ((row >> 1) & 3);       // pre-swizzled source slot
        int ar = m0 + row; if (ar > Mloc - 1) ar = Mloc - 1;
        ga[j] = Ab + (size_t)ar * K + subs * 8;
        gb[j] = Bb + (size_t)(n0 + row) * K + subs * 8;
        lo[j] = flat * 8;                        // linear LDS dest
    }
    floatx4 acc[4][4];
#pragma unroll
    for (int i = 0; i < 4; ++i)
#pragma unroll
        for (int j = 0; j < 4; ++j) acc[i][j] = (floatx4){0.f, 0.f, 0.f, 0.f};

    int wm = (wave >> 1) * 64, wn = (wave & 1) * 64;
    int fr = lane & 15, q = lane >> 4;
    int qs = q ^ ((fr >> 1) & 3);                // read slot after swizzle

    int nk = K >> 5;
    auto stage = [&](int buf, int t) {
        int k0 = t << 5;
        gl_lds16(ga[0] + k0, As[buf] + lo[0]);
        gl_lds16(gb[0] + k0, Bs[buf] + lo[0]);
        gl_lds16(ga[1] + k0, As[buf] + lo[1]);
        gl_lds16(gb[1] + k0, Bs[buf] + lo[1]);
    };
#pragma unroll
    for (int b = 0; b < NBUF - 1; ++b) stage(b, b);
    int cur = 0;
    for (int t = 0; t < nk; ++t) {
        int nxt = cur + (NBUF - 1); if (nxt >= NBUF) nxt -= NBUF;
        if (t + NBUF - 1 < nk) stage(nxt, t + NBUF - 1);
        int ahead = nk - 1 - t;
        if constexpr (EXPERT) {
            if (ahead >= 2)      asm volatile("s_waitcnt vmcnt(8)\n\ts_barrier" ::: "memory");
            else if (ahead == 1) asm volatile("s_waitcnt vmcnt(4)\n\ts_barrier" ::: "memory");
            else                 asm volatile("s_waitcnt vmcnt(0)\n\ts_barrier" ::: "memory");
        } else {
            if (ahead >= 3)      asm volatile("s_waitcnt vmcnt(12)\n\ts_barrier" ::: "memory");
            else if (ahead == 2) asm volatile("s_waitcnt vmcnt(8)\n\ts_barrier" ::: "memory");
            else if (ahead == 1) asm volatile("s_waitcnt vmcnt(4)\n\ts_barrier" ::: "memory");
            else                 asm volatile("s_waitcnt vmcnt(0)\n\ts_barrier" ::: "memory");
        }
        bf16x8 af[4], bfr[4];
        const unsigned short* Ac = As[cur];
        const unsigned short* Bc = Bs[cur];
#pragma unroll
        for (int f = 0; f < 4; ++f) {
            af[f]  = *(const bf16x8*)(Ac + (size_t)(wm + f * 16 + fr) * 32 + qs * 8);
            bfr[f] = *(const bf16x8*)(Bc + (size_t)(wn + f * 16 + fr) * 32 + qs * 8);
        }
#pragma unroll
        for (int fm = 0; fm < 4; ++fm)
#pragma unroll
            for (int fn = 0; fn < 4; ++fn)
                acc[fm][fn] = __builtin_amdgcn_mfma_f32_16x16x32_bf16(af[fm], bfr[fn], acc[fm][fn], 0, 0, 0);
        asm volatile("s_waitcnt lgkmcnt(0)\n\ts_barrier" ::: "memory");
        cur = cur + 1 == NBUF ? 0 : cur + 1;
    }
    int rb = q * 4;
#pragma unroll
    for (int fm = 0; fm < 4; ++fm) {
#pragma unroll
        for (int r = 0; r < 4; ++r) {
            int m = m0 + wm + fm * 16 + rb + r;
            if (m < Mloc) {
                float* cp = C + (size_t)(base + m) * N + n0 + wn + fr;
#pragma unroll
                for (int fn = 0; fn < 4; ++fn)
                    cp[fn * 16] = acc[fm][fn][r];
            }
        }
    }
}

// ------------------------------------------- beta / g small projections ----
__global__ void ba_kernel(const float* __restrict__ hidden,
                          const float* __restrict__ b_w, const float* __restrict__ a_w,
                          const float* __restrict__ A_log, const float* __restrict__ dt_bias,
                          const int* __restrict__ list, const int* __restrict__ cnt,
                          const int* __restrict__ basearr,
                          float* __restrict__ beta_c, float* __restrict__ g_c)
{
    int j = blockIdx.x, e = blockIdx.y;
    if (j >= cnt[e]) return;
    int gpos = basearr[e] + j;
    int tok = list[gpos];
    int lane = threadIdx.x;                      // 64
    const float* hr = hidden + (size_t)tok * Dm;
    float h[32];
#pragma unroll
    for (int i = 0; i < 32; ++i) h[i] = hr[lane + 64 * i];
    for (int c = 0; c < 12; ++c) {
        int col = c % 6;
        const float* W = ((c < 6) ? b_w : a_w) + (size_t)e * Dm * 6;
        float acc = 0.f;
#pragma unroll
        for (int i = 0; i < 32; ++i) acc += h[i] * W[(size_t)(lane + 64 * i) * 6 + col];
#pragma unroll
        for (int off = 1; off < 64; off <<= 1) acc += __shfl_xor(acc, off, 64);
        if (lane == 0) {
            if (c < 6) {
                beta_c[gpos * 6 + col] = 1.f / (1.f + expf(-acc));
            } else {
                float x = acc + dt_bias[col];
                float sp = (x > 20.f) ? x : log1pf(expf(x));
                g_c[gpos * 6 + col] = -expf(A_log[col]) * sp;
            }
        }
    }
}

// -------------------------------------- causal conv4 + silu (+ l2 norm) ----
template<bool GATHER>
__global__ void conv_norm_kernel(const float* __restrict__ X, int xstride,
                                 const float* __restrict__ convw,
                                 const int* __restrict__ list, const int* __restrict__ cnt,
                                 const int* __restrict__ basearr,
                                 float* __restrict__ outb, float scale)
{
    int j = blockIdx.x, e = blockIdx.y, h = blockIdx.z;
    if (j >= cnt[e]) return;
    int base = basearr[e];
    int gpos = base + j;
    int c = h * DKk + threadIdx.x;               // 256 threads
    float acc = 0.f;
#pragma unroll
    for (int tau = 0; tau < 4; ++tau) {
        int jj = j - 3 + tau;
        if (jj >= 0) {
            const float* row = GATHER ? (X + (size_t)list[base + jj] * xstride)
                                      : (X + (size_t)(base + jj) * xstride);
            acc += row[c] * convw[c * 4 + tau];
        }
    }
    float y = acc / (1.f + expf(-acc));          // silu
    float v = y * y;
#pragma unroll
    for (int off = 1; off < 64; off <<= 1) v += __shfl_xor(v, off, 64);
    __shared__ float red[4];
    if ((threadIdx.x & 63) == 0) red[threadIdx.x >> 6] = v;
    __syncthreads();
    float total = red[0] + red[1] + red[2] + red[3];
    outb[(size_t)gpos * KD + c] = y * rsqrtf(total + 1e-6f) * scale;
}

// v-conv reads fused kv rows, cols KD..KD+VD-1.
__global__ void conv_v_kernel(const float* __restrict__ X,
                              const float* __restrict__ convw,
                              const int* __restrict__ cnt, const int* __restrict__ basearr,
                              float* __restrict__ outb)
{
    int j = blockIdx.x, e = blockIdx.y;
    if (j >= cnt[e]) return;
    int base = basearr[e];
    int gpos = base + j;
    int c = blockIdx.z * 256 + threadIdx.x;      // 12 * 256 = 3072
    float acc = 0.f;
#pragma unroll
    for (int tau = 0; tau < 4; ++tau) {
        int jj = j - 3 + tau;
        if (jj >= 0) acc += X[(size_t)(base + jj) * QGW + KD + c] * convw[c * 4 + tau];
    }
    outb[(size_t)gpos * VD + c] = acc / (1.f + expf(-acc));
}

// ------------------------------------------------ qk = q . k precompute ----
__global__ void qk_kernel(const float* __restrict__ qn, const float* __restrict__ kn,
                          float* __restrict__ qk_c)
{
    int gpos = blockIdx.x, h = blockIdx.y;
    int lane = threadIdx.x;                      // 64
    const float4* qp = (const float4*)(qn + (size_t)gpos * KD + h * DKk);
    const float4* kp = (const float4*)(kn + (size_t)gpos * KD + h * DKk);
    float4 a = qp[lane], b = kp[lane];
    float acc = a.x * b.x + a.y * b.y + a.z * b.z + a.w * b.w;
#pragma unroll
    for (int off = 1; off < 64; off <<= 1) acc += __shfl_xor(acc, off, 64);
    if (lane == 0) qk_c[(size_t)gpos * Hh + h] = acc;
}

// --------------------------------------------- gated delta rule (serial) ----
// Geometry = verified R4 config (266-281 us): grid (16,H,E)=768 blocks,
// 3 blocks/CU single pass; thread = (kpart 0..7, vcol 0..31); LDS-staged k/q
// (CH=4 dbuf, counted vmcnt(2)); scalars prefetched; qk hoisted.
// R10: the kernel is ISSUE-bound (VALUBusy 68% + DS issue ~25% of the
// ~1100cyc/step). Dot products + state update rewritten as floatx4 vector
// ops via __builtin_elementwise_fma -> llvm.fma.v4f32 -> v_pk_fma_f32 pairs
// (gfx90a+ packed f32: 1 inst = 2 FMA), halving VALU instructions/step
// (~130 -> ~75). Math is bit-identical (same fma ops, same order).
__global__ __launch_bounds__(256, 3)
void recurrence_kernel(const float* __restrict__ qn, const float* __restrict__ kn,
                       const float* __restrict__ vc,
                       const float* __restrict__ beta_c, const float* __restrict__ g_c,
                       const float* __restrict__ qk_c,
                       const int* __restrict__ cnt, const int* __restrict__ basearr,
                       float* __restrict__ o_c)
{
    int vb = blockIdx.x, h = blockIdx.y, e = blockIdx.z;
    int n = cnt[e], base = basearr[e];
    if (n <= 0) return;
    int tid = threadIdx.x;
    int kpart = tid & 7, vcol = tid >> 3;
    int v = vb * 32 + vcol;
    int wv = tid >> 6, lane = tid & 63;

    __shared__ float lk[2][CH][256];             // 8 KB
    __shared__ float lq[2][CH][256];             // 8 KB

    const float* kb = kn + (size_t)base * KD + h * DKk;
    const float* qb = qn + (size_t)base * KD + h * DKk;
    const float* vp = vc + (size_t)base * VD + h * DVv + v;
    const float* gp = g_c    + (size_t)base * Hh + h;
    const float* bp = beta_c + (size_t)base * Hh + h;
    const float* xp = qk_c   + (size_t)base * Hh + h;
    float* op = o_c + (size_t)base * VD + h * DVv + v;

    floatx4 s[8];
#pragma unroll
    for (int i = 0; i < 8; ++i) s[i] = (floatx4){0.f, 0.f, 0.f, 0.f};

    int nch = (n + CH - 1) / CH;

    auto stageKQ = [&](int buf, int c) {
        int jj = c * CH + wv; if (jj > n - 1) jj = n - 1;
        gl_lds16(kb + (size_t)jj * KD + lane * 4, &lk[buf][wv][lane * 4]);
        gl_lds16(qb + (size_t)jj * KD + lane * 4, &lq[buf][wv][lane * 4]);
    };

    float vA[CH], gA[CH], bA[CH], xA[CH];
    float vB[CH], gB[CH], bB[CH], xB[CH];

    auto loadScal = [&](float (&V)[CH], float (&G)[CH], float (&B)[CH], float (&X)[CH], int c) {
#pragma unroll
        for (int u = 0; u < CH; ++u) {
            int jj = c * CH + u; if (jj > n - 1) jj = n - 1;
            V[u] = vp[(size_t)jj * VD];
            G[u] = gp[(size_t)jj * Hh];
            B[u] = bp[(size_t)jj * Hh];
            X[u] = xp[(size_t)jj * Hh];
        }
    };

    auto computeChunk = [&](const float (&Lk)[CH][256], const float (&Lq)[CH][256],
                            const float (&V)[CH], const float (&G)[CH],
                            const float (&B)[CH], const float (&X)[CH], int c) {
#pragma unroll
        for (int u = 0; u < CH; ++u) {
            // lane owns k-dims {kpart*4 + j + i*32}: conflict-free banks.
            const float* Lku = &Lk[u][kpart * 4];
            const float* Lqu = &Lq[u][kpart * 4];
            floatx4 pa0 = (floatx4){0.f,0.f,0.f,0.f}, pa1 = (floatx4){0.f,0.f,0.f,0.f};
            floatx4 ra0 = (floatx4){0.f,0.f,0.f,0.f}, ra1 = (floatx4){0.f,0.f,0.f,0.f};
            floatx4 kk[8];
#pragma unroll
            for (int i = 0; i < 8; ++i) {
                kk[i] = *(const floatx4*)(Lku + i * 32);
                floatx4 qq = *(const floatx4*)(Lqu + i * 32);
                if (i & 1) {
                    pa1 = __builtin_elementwise_fma(kk[i], s[i], pa1);
                    ra1 = __builtin_elementwise_fma(qq,    s[i], ra1);
                } else {
                    pa0 = __builtin_elementwise_fma(kk[i], s[i], pa0);
                    ra0 = __builtin_elementwise_fma(qq,    s[i], ra0);
                }
            }
            floatx4 pa = pa0 + pa1, ra = ra0 + ra1;
            float p = (pa.x + pa.y) + (pa.z + pa.w);
            float r = (ra.x + ra.y) + (ra.z + ra.w);
#pragma unroll
            for (int m = 1; m < 8; m <<= 1) {
                p += __shfl_xor(p, m, 64);
                r += __shfl_xor(r, m, 64);
            }
            float eg = __expf(G[u]);
            float delta = (V[u] - p * eg) * B[u];
            float out = fmaf(X[u], delta, eg * r);
            floatx4 egv = (floatx4){eg, eg, eg, eg};
            floatx4 dv  = (floatx4){delta, delta, delta, delta};
#pragma unroll
            for (int i = 0; i < 8; ++i)
                s[i] = __builtin_elementwise_fma(egv, s[i], kk[i] * dv);
            int j = c * CH + u;
            if (kpart == 0 && j < n) op[(size_t)j * VD] = out;
        }
    };

    stageKQ(0, 0);
    loadScal(vA, gA, bA, xA, 0);
    stageKQ(1, 1);
    asm volatile("s_waitcnt vmcnt(2)\n\ts_barrier" ::: "memory");

    for (int c = 0; c < nch; c += 2) {
        loadScal(vB, gB, bB, xB, c + 1);
        computeChunk(lk[0], lq[0], vA, gA, bA, xA, c);
        __syncthreads();
        stageKQ(0, c + 2);
        asm volatile("s_waitcnt vmcnt(2)\n\ts_barrier" ::: "memory");
        if (c + 1 >= nch) break;
        loadScal(vA, gA, bA, xA, c + 2);
        computeChunk(lk[1], lq[1], vB, gB, bB, xB, c + 1);
        __syncthreads();
        stageKQ(1, c + 3);
        asm volatile("s_waitcnt vmcnt(2)\n\ts_barrier" ::: "memory");
    }
    asm volatile("s_waitcnt vmcnt(0)" ::: "memory");
}

// ------------------------------- combine + gated RMSNorm (swish gate) -------
__global__ void combine_kernel(const float* __restrict__ o_c, const float* __restrict__ qg,
                               const float* __restrict__ norm_w,
                               const int* __restrict__ posg, const float* __restrict__ w01,
                               unsigned short* __restrict__ ocg)
{
    int t = blockIdx.x, h = blockIdx.y;
    int p0 = posg[2 * t], p1 = posg[2 * t + 1];
    float w0 = w01[2 * t], w1 = w01[2 * t + 1];
    int v0 = threadIdx.x, v1 = threadIdx.x + 256;
    size_t r0 = (size_t)p0 * VD + h * DVv, r1 = (size_t)p1 * VD + h * DVv;
    float a  = w0 * o_c[r0 + v0] + w1 * o_c[r1 + v0];
    float b2 = w0 * o_c[r0 + v1] + w1 * o_c[r1 + v1];
    float val = a * a + b2 * b2;
#pragma unroll
    for (int off = 1; off < 64; off <<= 1) val += __shfl_xor(val, off, 64);
    __shared__ float red[4];
    if ((threadIdx.x & 63) == 0) red[threadIdx.x >> 6] = val;
    __syncthreads();
    float total = red[0] + red[1] + red[2] + red[3];
    float rms = rsqrtf(total / 512.f + 1e-5f);
    size_t og = (size_t)t * VD + h * DVv;
    size_t gq = (size_t)t * QGW + KD + h * DVv;
    float g0 = qg[gq + v0], g1 = qg[gq + v1];
    ocg[og + v0] = f2bf(a  * rms * norm_w[v0] * g0 / (1.f + expf(-g0)));
    ocg[og + v1] = f2bf(b2 * rms * norm_w[v1] * g1 / (1.f + expf(-g1)));
}

// ------------------------------------------------------------------ host ----
extern "C" void kernel_launch(void* const* d_in, const int* in_sizes, int n_in,
                              void* d_out, int out_size, void* d_ws, size_t ws_size,
                              hipStream_t stream)
{
    const float* hidden   = (const float*)d_in[0];
    const float* q_w      = (const float*)d_in[1];
    const float* gate_w   = (const float*)d_in[2];
    const float* k_w      = (const float*)d_in[3];
    const float* v_w      = (const float*)d_in[4];
    const float* b_w      = (const float*)d_in[5];
    const float* a_w      = (const float*)d_in[6];
    const float* A_log    = (const float*)d_in[7];
    const float* dt_bias  = (const float*)d_in[8];
    const float* q_conv_w = (const float*)d_in[9];
    const float* k_conv_w = (const float*)d_in[10];
    const float* v_conv_w = (const float*)d_in[11];
    const float* g_w      = (const float*)d_in[12];
    const float* norm_w   = (const float*)d_in[13];
    const float* o_w      = (const float*)d_in[14];
    float* outp = (float*)d_out;

    float* f = (float*)d_ws;
    size_t off = 0;
    auto alloc = [&](size_t n) { float* p = f + off; off += (n + 3) & ~(size_t)3; return p; };
    float* qg     = alloc((size_t)1024 * QGW);    // [t][0:1536]=qh, [1536:4608]=gg
    float* kvraw  = alloc((size_t)2048 * QGW);    // [slot][0:1536]=kraw, [1536:4608]=vraw
    float* qn     = alloc((size_t)2048 * 1536);
    float* kn     = alloc((size_t)2048 * 1536);
    float* vconv  = alloc((size_t)2048 * 3072);
    float* o_c    = alloc((size_t)2048 * 3072);
    float* beta_c = alloc(2048 * 6);
    float* g_c    = alloc(2048 * 6);
    float* qk_c   = alloc(2048 * 6);
    float* w01f   = alloc(2048);

    unsigned short* u = (unsigned short*)(f + off);
    size_t uoff = 0;
    auto ualloc = [&](size_t n) { unsigned short* p = u + uoff; uoff += (n + 7) & ~(size_t)7; return p; };
    unsigned short* hidden_bf = ualloc((size_t)1024 * 2048);
    unsigned short* xe_c      = ualloc((size_t)2048 * 2048);
    unsigned short* ocg       = ualloc((size_t)1024 * 3072);
    unsigned short* qg_wT     = ualloc((size_t)QGW * 2048);       // q rows 0-1535, g rows 1536-4607
    unsigned short* kv_wT     = ualloc((size_t)8 * QGW * 2048);   // per e: k rows 0-1535, v rows 1536-4607
    unsigned short* o_wT      = ualloc((size_t)3072 * 2048);

    int* ib      = (int*)(u + uoff);
    int* sel01   = ib;
    int* list_c  = ib + 2048;
    int* posg    = ib + 4096;
    int* cnt     = ib + 6144;
    int* basearr = ib + 6152;

    const size_t EST = (size_t)2048 * QGW;       // expert stride in fused kv_wT

    router_kernel<<<1024, 64, 0, stream>>>(hidden, gate_w, sel01, w01f);
    dispatch_kernel<<<1, 1024, 0, stream>>>(sel01, list_c, posg, cnt, basearr);

    cast_bf16_kernel<<<2048, 256, 0, stream>>>(hidden, hidden_bf);
    gather_cast_kernel<<<2048, 256, 0, stream>>>(hidden, list_c, xe_c);
    transpose_cast_kernel<<<dim3(64, 48, 1), 256, 0, stream>>>(q_w, qg_wT, 2048, 1536, 0);
    transpose_cast_kernel<<<dim3(64, 96, 1), 256, 0, stream>>>(g_w, qg_wT + (size_t)1536 * 2048, 2048, 3072, 0);
    transpose_cast_kernel<<<dim3(64, 48, 8), 256, 0, stream>>>(k_w, kv_wT, 2048, 1536, EST);
    transpose_cast_kernel<<<dim3(64, 96, 8), 256, 0, stream>>>(v_w, kv_wT + (size_t)1536 * 2048, 2048, 3072, EST);
    transpose_cast_kernel<<<dim3(96, 64, 1), 256, 0, stream>>>(o_w, o_wT, 3072, 2048, 0);

    gemm_bf16<false><<<dim3(8, 36), 256, 0, stream>>>(hidden_bf, qg_wT, qg, nullptr, nullptr, 1024, 2048, QGW);
    gemm_bf16<true ><<<dim3(36, 8, 8), 256, 0, stream>>>(xe_c, kv_wT, kvraw, cnt, basearr, 0, 2048, QGW);

    ba_kernel<<<dim3(1024, 8), 64, 0, stream>>>(hidden, b_w, a_w, A_log, dt_bias,
                                                list_c, cnt, basearr, beta_c, g_c);

    conv_norm_kernel<true ><<<dim3(1024, 8, 6), 256, 0, stream>>>(qg,    QGW, q_conv_w, list_c, cnt, basearr, qn, 0.0625f);
    conv_norm_kernel<false><<<dim3(1024, 8, 6), 256, 0, stream>>>(kvraw, QGW, k_conv_w, list_c, cnt, basearr, kn, 1.0f);
    conv_v_kernel<<<dim3(1024, 8, 12), 256, 0, stream>>>(kvraw, v_conv_w, cnt, basearr, vconv);

    qk_kernel<<<dim3(2048, 6), 64, 0, stream>>>(qn, kn, qk_c);

    recurrence_kernel<<<dim3(16, 6, 8), 256, 0, stream>>>(qn, kn, vconv, beta_c, g_c, qk_c,
                                                          cnt, basearr, o_c);

    combine_kernel<<<dim3(1024, 6), 256, 0, stream>>>(o_c, qg, norm_w, posg, w01f, ocg);
    gemm_bf16<false><<<dim3(8, 16), 256, 0, stream>>>(ocg, o_wT, outp, nullptr, nullptr, 1024, 3072, 2048);
}